// Round 25
// baseline (150.649 us; speedup 1.0000x reference)
//
#include <hip/hip_runtime.h>

typedef unsigned short u16;
typedef unsigned int u32;
typedef __attribute__((ext_vector_type(8))) short bf16x8;
typedef __attribute__((ext_vector_type(4))) float f32x4;

__device__ __forceinline__ float b2f(u16 h) {
  union { u32 u; float f; } v; v.u = ((u32)h) << 16; return v.f;
}
__device__ __forceinline__ u16 f2b(float x) {
  union { float f; u32 u; } v; v.f = x;
  u32 u = v.u;
  return (u16)((u + 0x7FFFu + ((u >> 16) & 1u)) >> 16);  // RTN-even
}
__device__ __forceinline__ void up2(u32 u, float& lo, float& hi) {
  union { u32 x; float f; } a, b;
  a.x = u << 16; b.x = u & 0xFFFF0000u;
  lo = a.f; hi = b.f;
}
__device__ __forceinline__ u32 pk2(float lo, float hi) {
  return (u32)f2b(lo) | ((u32)f2b(hi) << 16);
}

// ---------------- prep: weight transposes / folds (bf16) ----------------
// wcomb: 10 chunks x 12288 u16 (GEMM1 A-frags + GEMM2 B-frags, frag order)
// wpk:  conv3 weights, contiguous per (ks,tap): 8KB fragment blobs
__global__ __launch_bounds__(256) void k_prep(
    const float* __restrict__ mod_w, const float* __restrict__ conv1_w,
    const float* __restrict__ m_items, const float* __restrict__ conv2_w,
    const float* __restrict__ wf_pre_w, const float* __restrict__ wf_post_w,
    const float* __restrict__ wf_bn_g, const float* __restrict__ pe_w,
    const float* __restrict__ exp_w, const float* __restrict__ up_w,
    u16* __restrict__ wcomb, u16* __restrict__ c2F,
    u16* __restrict__ wpreF, u16* __restrict__ wpk, u16* __restrict__ pewB,
    u16* __restrict__ expB, u16* __restrict__ upF)
{
  int idx = blockIdx.x * 256 + threadIdx.x;
  if (idx < 122880) {
    int chunk = idx / 12288, r = idx % 12288;
    float val;
    if (r < 8192) {
      int e = r & 7, lane = (r >> 3) & 63, fr = r >> 9;   // fr 0..15
      int ks = fr >> 2, ct = fr & 3;
      int chan = chunk * 64 + ct * 16 + (lane & 15);
      int c = ks * 32 + ((lane >> 4) << 3) + e;
      val = mod_w[chan * 128 + c];
    } else {
      int r2 = r - 8192;
      int e = r2 & 7, lane = (r2 >> 3) & 63, fr = r2 >> 9; // fr 0..7
      int kt = fr >> 2, nt = fr & 3;
      int o = nt * 16 + (lane & 15);
      int k = chunk * 64 + kt * 32 + ((lane >> 4) << 3) + e;
      val = conv1_w[o * 640 + k] * m_items[k];
    }
    wcomb[idx] = f2b(val);
  } else if (idx < 131072) {
    int i = idx - 122880;
    c2F[i] = f2b(conv2_w[i]);
  } else if (idx < 147456) {
    int i = idx - 131072;
    wpreF[i] = f2b(wf_pre_w[i]);
  } else if (idx < 294912) {
    int i2 = idx - 147456;
    int e = i2 & 7;
    int r = i2 >> 3;
    int lane = r & 63; r >>= 6;
    int n = r & 7; r >>= 3;          // r = ks*9+tap, 0..35
    int tap = r % 9, ks = r / 9;
    int o = (n << 4) + (lane & 15);
    int ic = (ks << 5) + ((lane >> 4) << 3) + e;
    int dy = tap / 3, dx = tap % 3;
    float scale = wf_bn_g[o] * rsqrtf(1.f + 1e-5f);
    wpk[i2] = f2b(wf_post_w[((o * 128 + ic) * 3 + dy) * 3 + dx] * scale);
  } else if (idx < 557056) {
    int i = idx - 294912;            // 0..262143
    int e = i & 7;
    int r = i >> 3;
    int lane = r & 63; r >>= 6;
    int n = r & 7;
    int gks = r >> 3;                // 0..63
    int o = (n << 4) + (lane & 15);
    int kp = (gks << 5) + ((lane >> 4) << 3) + e;   // k' index
    int p = kp >> 9, c = (kp >> 2) & 127, q = kp & 3;
    int k = c * 16 + p * 4 + q;
    pewB[i] = f2b(pe_w[o * 2048 + k]);
  } else if (idx < 622592) {
    int i = idx - 557056;            // 0..65535
    int j = i >> 7, c = i & 127;
    expB[i] = f2b(exp_w[c * 512 + j]);
  } else if (idx < 626688) {
    int i = idx - 622592;            // 0..4095
    upF[i] = f2b(up_w[i]);
  }
}

// ---------------- kernel A: fused read() -> Snp [4096 patches][2048] bf16 ---
__global__ __launch_bounds__(256) void k_read(
    const float* __restrict__ S, const u16* __restrict__ wcomb,
    const u16* __restrict__ c2F,
    const float* __restrict__ mod_b,
    const float* __restrict__ conv1_b, const float* __restrict__ conv2_b,
    u16* __restrict__ Snp)
{
  __shared__ u16 xs[16384];        // [pix=128][c=128] bf16, XOR-swizzled (32KB)
  __shared__ u16 modL[8192];       // [pix=128][kk=64] bf16, XOR-swizzled (16KB)
  __shared__ u16 wbuf[12288];      // staged weight fragments (24KB)
  __shared__ float rn[128];
  __shared__ float ps[2][128];
  __shared__ float mbL[640];

  const int t = threadIdx.x;
  const int b = blockIdx.x >> 7;
  const int y = blockIdx.x & 127;
  const int hw0 = y << 7;

  { // stage x (unnormalized bf16) + sumsq
    const int pix = t & 127, ch = t >> 7;
    const float* Sp = S + ((size_t)b << 21) + (size_t)hw0 + pix;
    float ss = 0.f;
    #pragma unroll
    for (int c0 = 0; c0 < 64; c0 += 8) {
      float v[8]; u32 pkv[4];
      #pragma unroll
      for (int j = 0; j < 8; ++j) {
        v[j] = Sp[(size_t)(ch * 64 + c0 + j) << 14];
        ss += v[j] * v[j];
      }
      #pragma unroll
      for (int j = 0; j < 4; ++j) pkv[j] = pk2(v[2 * j], v[2 * j + 1]);
      int e = pix * 256 + (ch * 64 + c0) * 2;
      e ^= (pix & 7) << 4;
      *(uint4*)((char*)xs + e) = *(const uint4*)pkv;
    }
    ps[ch][pix] = ss;
  }
  for (int i = t; i < 640; i += 256) mbL[i] = mod_b[i];
  __syncthreads();
  if (t < 128) rn[t] = 1.f / fmaxf(sqrtf(ps[0][t] + ps[1][t]), 1e-12f);

  const int w = t >> 6, l = t & 63;
  const int g = l >> 4, cl = l & 15;
  const int pxw = w << 5;
  const int swz = (cl & 7) << 4;

  __syncthreads();
  float rncol[2] = { rn[pxw + cl], rn[pxw + 16 + cl] };

  f32x4 acc2[2][4];
  #pragma unroll
  for (int pt = 0; pt < 2; ++pt)
    #pragma unroll
    for (int nt = 0; nt < 4; ++nt) acc2[pt][nt] = (f32x4){0.f, 0.f, 0.f, 0.f};

  for (int i = 0; i < 10; ++i) {
    const int n0 = i << 6;
    __syncthreads();   // prior iteration's wbuf reads complete
    {
      const u16* wsrc = wcomb + i * 12288;
      #pragma unroll
      for (int j = 0; j < 6; ++j) {
        uint4 v = *(const uint4*)(wsrc + (((j << 8) + t) << 3));
        *(uint4*)((char*)wbuf + (((j << 8) + t) << 4)) = v;
      }
    }
    __syncthreads();   // wbuf ready

    f32x4 acc1[4][2];
    #pragma unroll
    for (int ct = 0; ct < 4; ++ct)
      #pragma unroll
      for (int pt = 0; pt < 2; ++pt) acc1[ct][pt] = (f32x4){0.f, 0.f, 0.f, 0.f};
    #pragma unroll
    for (int ks = 0; ks < 4; ++ks) {
      bf16x8 xf[2];
      #pragma unroll
      for (int pt = 0; pt < 2; ++pt) {
        int pix = pxw + (pt << 4) + cl;
        int e = (pix * 256 + ks * 64 + g * 16) ^ swz;
        xf[pt] = *(const bf16x8*)((const char*)xs + e);
      }
      #pragma unroll
      for (int ct = 0; ct < 4; ++ct) {
        bf16x8 wf = *(const bf16x8*)((const char*)wbuf + (((ks << 2) + ct) << 10) + (l << 4));
        acc1[ct][0] = __builtin_amdgcn_mfma_f32_16x16x32_bf16(wf, xf[0], acc1[ct][0], 0, 0, 0);
        acc1[ct][1] = __builtin_amdgcn_mfma_f32_16x16x32_bf16(wf, xf[1], acc1[ct][1], 0, 0, 0);
      }
    }

    #pragma unroll
    for (int pt = 0; pt < 2; ++pt) {
      int pix = pxw + (pt << 4) + cl;
      float rv = rncol[pt];
      #pragma unroll
      for (int ct = 0; ct < 4; ++ct) {
        float4 mb4 = *(const float4*)&mbL[n0 + (ct << 4) + (g << 2)];
        f32x4 a = acc1[ct][pt];
        float m[4];
        #pragma unroll
        for (int r = 0; r < 4; ++r) {
          float z = a[r] * rv + ((const float*)&mb4)[r];
          m[r] = __builtin_amdgcn_rcpf(1.f + __expf(-z));
        }
        u32 lo, hi;
        asm("v_cvt_pk_bf16_f32 %0, %1, %2" : "=v"(lo) : "v"(m[0]), "v"(m[1]));
        asm("v_cvt_pk_bf16_f32 %0, %1, %2" : "=v"(hi) : "v"(m[2]), "v"(m[3]));
        int e = (pix * 128 + ct * 32 + g * 8) ^ swz;
        uint2 st = { lo, hi };
        *(uint2*)((char*)modL + e) = st;
      }
    }

    #pragma unroll
    for (int kt = 0; kt < 2; ++kt) {
      bf16x8 af[2];
      #pragma unroll
      for (int pt = 0; pt < 2; ++pt) {
        int pix = pxw + (pt << 4) + cl;
        int e = (pix * 128 + kt * 64 + g * 16) ^ swz;
        af[pt] = *(const bf16x8*)((const char*)modL + e);
      }
      #pragma unroll
      for (int nt = 0; nt < 4; ++nt) {
        bf16x8 bfr = *(const bf16x8*)((const char*)wbuf + 16384 + (((kt << 2) + nt) << 10) + (l << 4));
        acc2[0][nt] = __builtin_amdgcn_mfma_f32_16x16x32_bf16(af[0], bfr, acc2[0][nt], 0, 0, 0);
        acc2[1][nt] = __builtin_amdgcn_mfma_f32_16x16x32_bf16(af[1], bfr, acc2[1][nt], 0, 0, 0);
      }
    }
  }

  // GEMM3: Sc = (x @ c2F^T) * rn
  f32x4 acc3[2][4];
  #pragma unroll
  for (int pt = 0; pt < 2; ++pt)
    #pragma unroll
    for (int nt = 0; nt < 4; ++nt) acc3[pt][nt] = (f32x4){0.f, 0.f, 0.f, 0.f};
  #pragma unroll
  for (int ks = 0; ks < 4; ++ks) {
    bf16x8 af[2];
    #pragma unroll
    for (int pt = 0; pt < 2; ++pt) {
      int pix = pxw + (pt << 4) + cl;
      int e = (pix * 256 + ks * 64 + g * 16) ^ swz;
      af[pt] = *(const bf16x8*)((const char*)xs + e);
    }
    #pragma unroll
    for (int nt = 0; nt < 4; ++nt) {
      bf16x8 bfr = *(const bf16x8*)&c2F[(size_t)((nt << 4) + cl) * 128 + ks * 32 + g * 8];
      acc3[0][nt] = __builtin_amdgcn_mfma_f32_16x16x32_bf16(af[0], bfr, acc3[0][nt], 0, 0, 0);
      acc3[1][nt] = __builtin_amdgcn_mfma_f32_16x16x32_bf16(af[1], bfr, acc3[1][nt], 0, 0, 0);
    }
  }

  // epilogue -> Snp[patch][k'], k' = p*512 + c*4 + q (bf16), p = y&3 fixed
  const int pgrp = (b << 5) + (y >> 2);
  u16* Srow = Snp + ((size_t)pgrp << 16) + ((y & 3) << 9);
  #pragma unroll
  for (int pt = 0; pt < 2; ++pt) {
    int pixr = pxw + (pt << 4) + (g << 2);
    float4 rn4 = *(const float4*)&rn[pixr];
    int pw = pixr >> 2;
    #pragma unroll
    for (int nt = 0; nt < 4; ++nt) {
      int c = (nt << 4) + cl;
      float b1 = conv1_b[c];
      f32x4 a2 = acc2[pt][nt];
      uint2 s0 = { pk2(a2[0] + b1, a2[1] + b1), pk2(a2[2] + b1, a2[3] + b1) };
      *(uint2*)&Srow[((size_t)pw << 11) + (c << 2)] = s0;
      float b2 = conv2_b[c];
      f32x4 a3 = acc3[pt][nt];
      uint2 s1v = { pk2(a3[0] * rn4.x + b2, a3[1] * rn4.y + b2),
                    pk2(a3[2] * rn4.z + b2, a3[3] * rn4.w + b2) };
      *(uint2*)&Srow[((size_t)pw << 11) + ((c + 64) << 2)] = s1v;
    }
  }
}

// ------- kernel BC: fused PatchEmbed GEMM + LN -> (LDS) -> PatchExpand ------
// 512 threads / 8 waves: phase-1 each wave owns ONE 16-chan n-tile; phase-3
// jt = w*4+jj; phase-4 pixl = (w*2+mt4)*16+cl. LDS identical to 4-wave build.
__global__ __launch_bounds__(512) void k_pe_ex(
    const u16* __restrict__ Snp, const u16* __restrict__ pewB,
    const float* __restrict__ pe_b, const float* __restrict__ pe_g,
    const float* __restrict__ pe_beta,
    const u16* __restrict__ expB,
    const float* __restrict__ fin_g, const float* __restrict__ fin_b,
    const u16* __restrict__ upF, const float* __restrict__ up_b,
    u16* __restrict__ M1b)
{
  __shared__ u16 As[8192];        // 16 patches x 512 k, XOR-swizzled (16KB)
  __shared__ float fln[16][132];  // 8.25KB
  __shared__ u16 fb[2048];        // [16 patches][128] bf16, XOR (p&7)<<4 (4KB)
  __shared__ u16 feL[8192];       // (16KB)
  __shared__ u16 feL2[8192];      // (16KB)
  __shared__ float lng[32], lnb[32];
  const int t = threadIdx.x, bx = blockIdx.x;
  const int w = t >> 6, l = t & 63;
  const int g = l >> 4, cl = l & 15;
  const size_t gbase = (size_t)bx << 15;
  const int pg0 = bx << 4;

  if (t < 32) { lng[t] = fin_g[t]; lnb[t] = fin_b[t]; }

  // ---------------- phase 1: PatchEmbed GEMM (M=16, N=128, K=2048) ---------
  // wave w computes n-tile w (16 output chans) for all 16 patches.
  f32x4 acc = (f32x4){0.f, 0.f, 0.f, 0.f};

  for (int chunk = 0; chunk < 4; ++chunk) {
    __syncthreads();
    #pragma unroll
    for (int it = 0; it < 2; ++it) {
      int e8 = ((it << 9) + t) << 3;       // 1024 x 16B total
      int pl = e8 >> 9, kk = e8 & 511;
      uint4 v = *(const uint4*)&Snp[gbase + ((size_t)pl << 11) + (chunk << 9) + kk];
      int e = (((pl << 9) + kk) << 1) ^ ((pl & 7) << 4);
      *(uint4*)((char*)As + e) = v;
    }
    __syncthreads();
    for (int ks = 0; ks < 16; ++ks) {
      int kk = (ks << 5) + (g << 3);
      int e = (((cl << 9) + kk) << 1) ^ ((cl & 7) << 4);
      bf16x8 A = *(const bf16x8*)((const char*)As + e);
      int gks = (chunk << 4) + ks;
      bf16x8 B = *(const bf16x8*)&pewB[(size_t)((((gks << 3) + w) << 6) + l) << 3];
      acc = __builtin_amdgcn_mfma_f32_16x16x32_bf16(A, B, acc, 0, 0, 0);
    }
  }

  {
    int o = (w << 4) + cl;
    float pb = pe_b[o];
    #pragma unroll
    for (int r = 0; r < 4; ++r)
      fln[(g << 2) + r][o] = acc[r] + pb;
  }
  __syncthreads();

  // ------------- phase 2: LN over 128 chans -> fb (LDS, bf16) -------------
  if (t < 128) {
    int patch = t >> 3, sub = t & 7;
    float4 v0 = *(const float4*)&fln[patch][(sub << 4) + 0];
    float4 v1 = *(const float4*)&fln[patch][(sub << 4) + 4];
    float4 v2 = *(const float4*)&fln[patch][(sub << 4) + 8];
    float4 v3 = *(const float4*)&fln[patch][(sub << 4) + 12];
    float s1 = v0.x + v0.y + v0.z + v0.w + v1.x + v1.y + v1.z + v1.w
             + v2.x + v2.y + v2.z + v2.w + v3.x + v3.y + v3.z + v3.w;
    float s2 = v0.x*v0.x + v0.y*v0.y + v0.z*v0.z + v0.w*v0.w
             + v1.x*v1.x + v1.y*v1.y + v1.z*v1.z + v1.w*v1.w
             + v2.x*v2.x + v2.y*v2.y + v2.z*v2.z + v2.w*v2.w
             + v3.x*v3.x + v3.y*v3.y + v3.z*v3.z + v3.w*v3.w;
    s1 += __shfl_xor(s1, 1); s2 += __shfl_xor(s2, 1);
    s1 += __shfl_xor(s1, 2); s2 += __shfl_xor(s2, 2);
    s1 += __shfl_xor(s1, 4); s2 += __shfl_xor(s2, 4);
    float m = s1 * (1.f / 128.f);
    float var = s2 * (1.f / 128.f) - m * m;
    float rs = rsqrtf(var + 1e-5f);
    int o0 = sub << 4;
    #pragma unroll
    for (int i = 0; i < 4; ++i) {
      float4 vv = (i == 0) ? v0 : (i == 1) ? v1 : (i == 2) ? v2 : v3;
      float4 gv = *(const float4*)&pe_g[o0 + (i << 2)];
      float4 bv = *(const float4*)&pe_beta[o0 + (i << 2)];
      uint2 st = { pk2((vv.x - m) * rs * gv.x + bv.x, (vv.y - m) * rs * gv.y + bv.y),
                   pk2((vv.z - m) * rs * gv.z + bv.z, (vv.w - m) * rs * gv.w + bv.w) };
      int c = o0 + (i << 2);
      int e = (patch * 256 + c * 2) ^ ((patch & 7) << 4);
      *(uint2*)((char*)fb + e) = st;
    }
  }
  __syncthreads();

  // ------------- phase 3: PatchExpand GEMM (swapped) + LN(32) -------------
  // wave w: jt = w*4 + jj, jj < 4  (32 jt tiles over 8 waves)
  f32x4 acc1[4];
  #pragma unroll
  for (int jj = 0; jj < 4; ++jj) acc1[jj] = (f32x4){0.f, 0.f, 0.f, 0.f};
  #pragma unroll
  for (int ks = 0; ks < 4; ++ks) {
    int e = (cl * 256 + ks * 64 + g * 16) ^ ((cl & 7) << 4);
    bf16x8 ff = *(const bf16x8*)((const char*)fb + e);
    #pragma unroll
    for (int jj = 0; jj < 4; ++jj) {
      int jt = (w << 2) + jj;
      bf16x8 wf = *(const bf16x8*)&expB[(size_t)((jt << 4) + cl) * 128 + ks * 32 + g * 8];
      acc1[jj] = __builtin_amdgcn_mfma_f32_16x16x32_bf16(wf, ff, acc1[jj], 0, 0, 0);
    }
  }
  // store: lane -> patch = cl, j0 = jt*16 + g*4 (4 consecutive j as bf16)
  #pragma unroll
  for (int jj = 0; jj < 4; ++jj) {
    int j0 = (((w << 2) + jj) << 4) + (g << 2);
    f32x4 a = acc1[jj];
    uint2 st = { pk2(a[0], a[1]), pk2(a[2], a[3]) };
    int e = (cl * 1024 + j0 * 2) ^ ((cl & 7) << 3);
    *(uint2*)((char*)feL + e) = st;
  }
  __syncthreads();

  if (t < 256) { // LN over 32-chan groups; thread t -> pixel t
    int patch = t >> 4, sub = t & 15;
    int rot = t & 15;
    int baseR = patch * 1024 + sub * 64;
    int xr = (patch & 7) << 3;
    float vals[32];
    float s1 = 0.f, s2 = 0.f;
    #pragma unroll
    for (int wd = 0; wd < 16; ++wd) {
      int ww = (wd + rot) & 15;
      u32 u = *(const u32*)((const char*)feL + ((baseR + ww * 4) ^ xr));
      float lo, hi; up2(u, lo, hi);
      vals[wd * 2] = lo; vals[wd * 2 + 1] = hi;
      s1 += lo + hi; s2 += lo * lo + hi * hi;
    }
    float m = s1 * (1.f / 32.f);
    float var = s2 * (1.f / 32.f) - m * m;
    float rs = rsqrtf(var + 1e-5f);
    int baseW = t * 64;
    int xw = (t & 3) << 4;           // 16B-granularity XOR
    #pragma unroll
    for (int wd = 0; wd < 16; ++wd) {
      int ww = (wd + rot) & 15;
      float lo = (vals[wd * 2]     - m) * rs * lng[ww * 2]     + lnb[ww * 2];
      float hi = (vals[wd * 2 + 1] - m) * rs * lng[ww * 2 + 1] + lnb[ww * 2 + 1];
      *(u32*)((char*)feL2 + ((baseW + ww * 4) ^ xw)) = pk2(lo, hi);
    }
  }
  __syncthreads();

  // up-proj (swapped): wave w handles pixl half-tiles (w*2+mt4), mt4 < 2.
  #pragma unroll
  for (int mt4 = 0; mt4 < 2; ++mt4) {
    int pixl = (((w << 1) + mt4) << 4) + cl;
    int e = (pixl * 64 + g * 16) ^ ((pixl & 3) << 4);
    bf16x8 fef = *(const bf16x8*)((const char*)feL2 + e);
    int pglob = pg0 + (pixl >> 4);
    int sub = pixl & 15;
    int bb = pglob >> 10, ph = (pglob >> 5) & 31, pw = pglob & 31;
    int yy = (ph << 2) + (sub >> 2), xx = (pw << 2) + (sub & 3);
    size_t mbase = ((size_t)(((bb << 7) + yy) << 7) + xx) << 7;
    f32x4 accu[8];
    #pragma unroll
    for (int nt = 0; nt < 8; ++nt) {
      bf16x8 wfu = *(const bf16x8*)&upF[((nt << 4) + cl) * 32 + g * 8];
      accu[nt] = __builtin_amdgcn_mfma_f32_16x16x32_bf16(
          wfu, fef, (f32x4){0.f, 0.f, 0.f, 0.f}, 0, 0, 0);
    }
    #pragma unroll
    for (int nt = 0; nt < 8; ++nt) {
      int o0 = (nt << 4) + (g << 2);
      float4 ub4 = *(const float4*)&up_b[o0];
      f32x4 a = accu[nt];
      uint2 st = { pk2(a[0] + ub4.x, a[1] + ub4.y),
                   pk2(a[2] + ub4.z, a[3] + ub4.w) };
      *(uint2*)&M1b[mbase + o0] = st;
    }
  }
}

// --- kernel E: fused WF-combine + 3x3 conv (MFMA implicit GEMM) + BN + ReLU6
// Per block: stage Q (10x10 halo x 128c, bf16, zero-filled OOB) into qs (LDS
// space reused by wb after the QW phase), compute
//   it[pix][o] = bf16(f0 * (Q@Wpre^T) + f1 * M1b)   (identical rounding to
// the old k_wf->Xn path), then the unchanged 6-phase conv3 main loop.
__global__ __launch_bounds__(256) void k_conv3(
    const float* __restrict__ Q, const u16* __restrict__ wpreF,
    const u16* __restrict__ M1b, const float* __restrict__ w2,
    const u16* __restrict__ wpk, const float* __restrict__ bnb,
    float* __restrict__ out)
{
  __shared__ u16 it[12800];    // 100 rows x 128 ic, XOR-swizzled (25.6KB)
  __shared__ u16 pool[24576];  // qs (first 12800 u16) then wb (48KB)
  u16* qs = pool;
  u16* wb = pool;
  const int t = threadIdx.x, bx = blockIdx.x;
  const int b = bx >> 8, rem = bx & 255;
  const int ty8 = (rem >> 4) << 3, tx8 = (rem & 15) << 3;
  const int y0 = ty8 - 1, x0 = tx8 - 1;

  float a0 = fmaxf(w2[0], 0.f), a1 = fmaxf(w2[1], 0.f);
  float inv = 1.f / (a0 + a1 + 1e-8f);
  float f0 = a0 * inv, f1 = a1 * inv;

  // ---- stage Q (NCHW fp32 -> bf16) into qs[100][128], it[]-identical layout
  for (int idx = t; idx < 1600; idx += 256) {
    int ri = idx >> 4, cc = idx & 15;
    int gy = y0 + ri / 10, gx = x0 + ri % 10;
    u32 pkv[4] = {0u, 0u, 0u, 0u};
    if (gy >= 0 && gy < 128 && gx >= 0 && gx < 128) {
      const float* Qp = Q + ((((size_t)(b << 7) + (cc << 3)) << 7) + gy) * 128 + gx;
      float v[8];
      #pragma unroll
      for (int j = 0; j < 8; ++j) v[j] = Qp[(size_t)j << 14];
      #pragma unroll
      for (int j = 0; j < 4; ++j) pkv[j] = pk2(v[2 * j], v[2 * j + 1]);
    }
    int e = (ri << 7) + (cc << 3);
    e ^= (ri & 7) << 3;
    *(uint4*)&qs[e] = *(const uint4*)pkv;
  }
  __syncthreads();

  const int w = t >> 6, l = t & 63;
  const int g = l >> 4, cl = l & 15;

  // ---- QW phase: it = f0*(qs @ Wpre^T) + f1*M1b  (7 pix tiles x 2 o-tiles)
  #pragma unroll
  for (int m = 0; m < 7; ++m) {
    int pix = (m << 4) + cl;
    int ri = (pix < 100) ? pix : 99;       // clamp tail reads (discarded)
    bf16x8 qf[4];
    #pragma unroll
    for (int ks = 0; ks < 4; ++ks) {
      int e = (ri << 7) + (ks << 5) + (g << 3);
      e ^= (ri & 7) << 3;
      qf[ks] = *(const bf16x8*)&qs[e];
    }
    #pragma unroll
    for (int ot2 = 0; ot2 < 2; ++ot2) {
      int ot = (w << 1) + ot2;
      f32x4 accq = (f32x4){0.f, 0.f, 0.f, 0.f};
      #pragma unroll
      for (int ks = 0; ks < 4; ++ks) {
        bf16x8 wf = *(const bf16x8*)&wpreF[(size_t)((ot << 4) + cl) * 128 + ks * 32 + g * 8];
        accq = __builtin_amdgcn_mfma_f32_16x16x32_bf16(wf, qf[ks], accq, 0, 0, 0);
      }
      if (pix < 100) {
        int gy = y0 + pix / 10, gx = x0 + pix % 10;
        int o0 = (ot << 4) + (g << 2);
        uint2 mv = {0u, 0u};
        if (gy >= 0 && gy < 128 && gx >= 0 && gx < 128)
          mv = *(const uint2*)&M1b[((((size_t)(b << 7) + gy) << 7) + gx) * 128 + o0];
        float m0, m1, m2, m3;
        up2(mv.x, m0, m1); up2(mv.y, m2, m3);
        uint2 st = { pk2(f0 * accq[0] + f1 * m0, f0 * accq[1] + f1 * m1),
                     pk2(f0 * accq[2] + f1 * m2, f0 * accq[3] + f1 * m3) };
        int e = (ri << 7) + o0;
        e ^= (ri & 7) << 3;
        *(uint2*)&it[e] = st;
      }
    }
  }

  f32x4 acc[4][2];
  #pragma unroll
  for (int m = 0; m < 4; ++m)
    #pragma unroll
    for (int nn = 0; nn < 2; ++nn)
      acc[m][nn] = (f32x4){0.f, 0.f, 0.f, 0.f};

  int ri0[4];
  #pragma unroll
  for (int m = 0; m < 4; ++m) {
    int p = (m << 4) + cl;
    ri0[m] = (p >> 3) * 10 + (p & 7);
  }

  #pragma unroll
  for (int p = 0; p < 6; ++p) {
    __syncthreads();   // prior phase's wb reads done (p=0: QW qs reads + it writes)
    { // stage 6 taps of B fragments: contiguous 48KB from wpk (12/thread)
      const u16* wsrc = wpk + p * 24576;
      #pragma unroll
      for (int j = 0; j < 12; ++j) {
        uint4 v = *(const uint4*)(wsrc + (((j << 8) + t) << 3));
        *(uint4*)((char*)wb + (((j << 8) + t) << 4)) = v;
      }
    }
    __syncthreads();   // wb ready

    #pragma unroll
    for (int tl = 0; tl < 6; ++tl) {
      const int q = p * 6 + tl;            // global (ks,tap) index 0..35
      const int ks = q / 9, tap = q % 9;
      const int dy = tap / 3, dx = tap % 3;
      bf16x8 A[4];
      #pragma unroll
      for (int m = 0; m < 4; ++m) {
        int ri = ri0[m] + dy * 10 + dx;
        int e = (ri << 7) + (ks << 5) + (g << 3);
        e ^= (ri & 7) << 3;
        A[m] = *(const bf16x8*)&it[e];
      }
      #pragma unroll
      for (int nn = 0; nn < 2; ++nn) {
        int n = (w << 1) + nn;
        bf16x8 B = *(const bf16x8*)((const char*)wb + (((tl << 3) + n) << 10) + (l << 4));
        #pragma unroll
        for (int m = 0; m < 4; ++m)
          acc[m][nn] = __builtin_amdgcn_mfma_f32_16x16x32_bf16(A[m], B, acc[m][nn], 0, 0, 0);
      }
    }
  }

  #pragma unroll
  for (int m = 0; m < 4; ++m) {
    int p = (m << 4) + (g << 2);
    int py = p >> 3, px = p & 7;
    #pragma unroll
    for (int nn = 0; nn < 2; ++nn) {
      int n = (w << 1) + nn;
      int o = (n << 4) + cl;
      float bb = bnb[o];
      f32x4 a = acc[m][nn];
      float4 v = { fminf(fmaxf(a[0] + bb, 0.f), 6.f),
                   fminf(fmaxf(a[1] + bb, 0.f), 6.f),
                   fminf(fmaxf(a[2] + bb, 0.f), 6.f),
                   fminf(fmaxf(a[3] + bb, 0.f), 6.f) };
      *(float4*)&out[((size_t)((b << 7) + o) << 14) + ((ty8 + py) << 7) + tx8 + px] = v;
    }
  }
}

extern "C" void kernel_launch(void* const* d_in, const int* in_sizes, int n_in,
                              void* d_out, int out_size, void* d_ws, size_t ws_size,
                              hipStream_t stream) {
  const float* Structure = (const float*)d_in[0];
  const float* query     = (const float*)d_in[1];
  const float* m_items   = (const float*)d_in[2];
  const float* mod_w     = (const float*)d_in[3];
  const float* mod_b     = (const float*)d_in[4];
  const float* conv1_w   = (const float*)d_in[5];
  const float* conv1_b   = (const float*)d_in[6];
  const float* conv2_w   = (const float*)d_in[7];
  const float* conv2_b   = (const float*)d_in[8];
  const float* pe_w      = (const float*)d_in[9];
  const float* pe_b      = (const float*)d_in[10];
  const float* pe_g      = (const float*)d_in[11];
  const float* pe_beta   = (const float*)d_in[12];
  const float* exp_w     = (const float*)d_in[13];
  const float* fin_g     = (const float*)d_in[14];
  const float* fin_b     = (const float*)d_in[15];
  const float* up_w      = (const float*)d_in[16];
  const float* up_b      = (const float*)d_in[17];
  const float* wf_w2     = (const float*)d_in[18];
  const float* wf_pre_w  = (const float*)d_in[19];
  const float* wf_post_w = (const float*)d_in[20];
  const float* wf_bn_g   = (const float*)d_in[21];
  const float* wf_bn_b   = (const float*)d_in[22];

  char* ws = (char*)d_ws;
  u16*   Snp = (u16*)(ws + 0);               // 16,777,216 B (bf16 im2col, k')
  u16*   expB = (u16*)(ws + 34603008);       //    131,072 B
  u16*   upF  = (u16*)(ws + 34734080);       //      8,192 B
  u16*   M1b = (u16*)(ws + 35651584);        // 16,777,216 B (bf16 NHWC)
  u16* wcomb = (u16*)(ws + 69206016);        // 245,760 B
  u16* c2F   = (u16*)(ws + 69451776);        //  16,384 B
  u16* wpreF = (u16*)(ws + 69468160);        //  32,768 B
  u16* wpk   = (u16*)(ws + 69500928);        // 294,912 B
  u16* pewB  = (u16*)(ws + 69795840);        // 524,288 B -> end 70,320,128 B

  k_prep<<<2448, 256, 0, stream>>>(mod_w, conv1_w, m_items, conv2_w, wf_pre_w,
                                   wf_post_w, wf_bn_g, pe_w, exp_w, up_w,
                                   wcomb, c2F, wpreF, wpk, pewB, expB, upF);
  k_read<<<512, 256, 0, stream>>>(Structure, wcomb, c2F, mod_b,
                                  conv1_b, conv2_b, Snp);
  k_pe_ex<<<256, 512, 0, stream>>>(Snp, pewB, pe_b, pe_g, pe_beta,
                                   expB, fin_g, fin_b, upF, up_b, M1b);
  k_conv3<<<1024, 256, 0, stream>>>(query, wpreF, M1b, wf_w2, wpk, wf_bn_b,
                                    (float*)d_out);
}

// Round 26
// 124.453 us; speedup vs baseline: 1.2105x; 1.2105x over previous
//
#include <hip/hip_runtime.h>

typedef unsigned short u16;
typedef unsigned int u32;
typedef __attribute__((ext_vector_type(8))) short bf16x8;
typedef __attribute__((ext_vector_type(4))) float f32x4;

__device__ __forceinline__ float b2f(u16 h) {
  union { u32 u; float f; } v; v.u = ((u32)h) << 16; return v.f;
}
__device__ __forceinline__ u16 f2b(float x) {
  union { float f; u32 u; } v; v.f = x;
  u32 u = v.u;
  return (u16)((u + 0x7FFFu + ((u >> 16) & 1u)) >> 16);  // RTN-even
}
__device__ __forceinline__ void up2(u32 u, float& lo, float& hi) {
  union { u32 x; float f; } a, b;
  a.x = u << 16; b.x = u & 0xFFFF0000u;
  lo = a.f; hi = b.f;
}
__device__ __forceinline__ u32 pk2(float lo, float hi) {
  return (u32)f2b(lo) | ((u32)f2b(hi) << 16);
}

// ---------------- prep: weight transposes / folds (bf16) ----------------
// wcomb: 10 chunks x 12288 u16 (GEMM1 A-frags + GEMM2 B-frags, frag order)
// wpk:  conv3 weights, contiguous per (ks,tap): 8KB fragment blobs
__global__ __launch_bounds__(256) void k_prep(
    const float* __restrict__ mod_w, const float* __restrict__ conv1_w,
    const float* __restrict__ m_items, const float* __restrict__ conv2_w,
    const float* __restrict__ wf_pre_w, const float* __restrict__ wf_post_w,
    const float* __restrict__ wf_bn_g, const float* __restrict__ pe_w,
    const float* __restrict__ exp_w, const float* __restrict__ up_w,
    u16* __restrict__ wcomb, u16* __restrict__ c2F,
    u16* __restrict__ wpreF, u16* __restrict__ wpk, u16* __restrict__ pewB,
    u16* __restrict__ expB, u16* __restrict__ upF)
{
  int idx = blockIdx.x * 256 + threadIdx.x;
  if (idx < 122880) {
    int chunk = idx / 12288, r = idx % 12288;
    float val;
    if (r < 8192) {
      int e = r & 7, lane = (r >> 3) & 63, fr = r >> 9;   // fr 0..15
      int ks = fr >> 2, ct = fr & 3;
      int chan = chunk * 64 + ct * 16 + (lane & 15);
      int c = ks * 32 + ((lane >> 4) << 3) + e;
      val = mod_w[chan * 128 + c];
    } else {
      int r2 = r - 8192;
      int e = r2 & 7, lane = (r2 >> 3) & 63, fr = r2 >> 9; // fr 0..7
      int kt = fr >> 2, nt = fr & 3;
      int o = nt * 16 + (lane & 15);
      int k = chunk * 64 + kt * 32 + ((lane >> 4) << 3) + e;
      val = conv1_w[o * 640 + k] * m_items[k];
    }
    wcomb[idx] = f2b(val);
  } else if (idx < 131072) {
    int i = idx - 122880;
    c2F[i] = f2b(conv2_w[i]);
  } else if (idx < 147456) {
    int i = idx - 131072;
    wpreF[i] = f2b(wf_pre_w[i]);
  } else if (idx < 294912) {
    int i2 = idx - 147456;
    int e = i2 & 7;
    int r = i2 >> 3;
    int lane = r & 63; r >>= 6;
    int n = r & 7; r >>= 3;          // r = ks*9+tap, 0..35
    int tap = r % 9, ks = r / 9;
    int o = (n << 4) + (lane & 15);
    int ic = (ks << 5) + ((lane >> 4) << 3) + e;
    int dy = tap / 3, dx = tap % 3;
    float scale = wf_bn_g[o] * rsqrtf(1.f + 1e-5f);
    wpk[i2] = f2b(wf_post_w[((o * 128 + ic) * 3 + dy) * 3 + dx] * scale);
  } else if (idx < 557056) {
    int i = idx - 294912;            // 0..262143
    int e = i & 7;
    int r = i >> 3;
    int lane = r & 63; r >>= 6;
    int n = r & 7;
    int gks = r >> 3;                // 0..63
    int o = (n << 4) + (lane & 15);
    int kp = (gks << 5) + ((lane >> 4) << 3) + e;   // k' index
    int p = kp >> 9, c = (kp >> 2) & 127, q = kp & 3;
    int k = c * 16 + p * 4 + q;
    pewB[i] = f2b(pe_w[o * 2048 + k]);
  } else if (idx < 622592) {
    int i = idx - 557056;            // 0..65535
    int j = i >> 7, c = i & 127;
    expB[i] = f2b(exp_w[c * 512 + j]);
  } else if (idx < 626688) {
    int i = idx - 622592;            // 0..4095
    upF[i] = f2b(up_w[i]);
  }
}

// ---------------- kernel A: fused read() -> Snp [4096 patches][2048] bf16 ---
__global__ __launch_bounds__(256) void k_read(
    const float* __restrict__ S, const u16* __restrict__ wcomb,
    const u16* __restrict__ c2F,
    const float* __restrict__ mod_b,
    const float* __restrict__ conv1_b, const float* __restrict__ conv2_b,
    u16* __restrict__ Snp)
{
  __shared__ u16 xs[16384];        // [pix=128][c=128] bf16, XOR-swizzled (32KB)
  __shared__ u16 modL[8192];       // [pix=128][kk=64] bf16, XOR-swizzled (16KB)
  __shared__ u16 wbuf[12288];      // staged weight fragments (24KB)
  __shared__ float rn[128];
  __shared__ float ps[2][128];
  __shared__ float mbL[640];

  const int t = threadIdx.x;
  const int b = blockIdx.x >> 7;
  const int y = blockIdx.x & 127;
  const int hw0 = y << 7;

  { // stage x (unnormalized bf16) + sumsq
    const int pix = t & 127, ch = t >> 7;
    const float* Sp = S + ((size_t)b << 21) + (size_t)hw0 + pix;
    float ss = 0.f;
    #pragma unroll
    for (int c0 = 0; c0 < 64; c0 += 8) {
      float v[8]; u32 pkv[4];
      #pragma unroll
      for (int j = 0; j < 8; ++j) {
        v[j] = Sp[(size_t)(ch * 64 + c0 + j) << 14];
        ss += v[j] * v[j];
      }
      #pragma unroll
      for (int j = 0; j < 4; ++j) pkv[j] = pk2(v[2 * j], v[2 * j + 1]);
      int e = pix * 256 + (ch * 64 + c0) * 2;
      e ^= (pix & 7) << 4;
      *(uint4*)((char*)xs + e) = *(const uint4*)pkv;
    }
    ps[ch][pix] = ss;
  }
  for (int i = t; i < 640; i += 256) mbL[i] = mod_b[i];
  __syncthreads();
  if (t < 128) rn[t] = 1.f / fmaxf(sqrtf(ps[0][t] + ps[1][t]), 1e-12f);

  const int w = t >> 6, l = t & 63;
  const int g = l >> 4, cl = l & 15;
  const int pxw = w << 5;
  const int swz = (cl & 7) << 4;

  __syncthreads();
  float rncol[2] = { rn[pxw + cl], rn[pxw + 16 + cl] };

  f32x4 acc2[2][4];
  #pragma unroll
  for (int pt = 0; pt < 2; ++pt)
    #pragma unroll
    for (int nt = 0; nt < 4; ++nt) acc2[pt][nt] = (f32x4){0.f, 0.f, 0.f, 0.f};

  for (int i = 0; i < 10; ++i) {
    const int n0 = i << 6;
    __syncthreads();   // prior iteration's wbuf reads complete
    {
      const u16* wsrc = wcomb + i * 12288;
      #pragma unroll
      for (int j = 0; j < 6; ++j) {
        uint4 v = *(const uint4*)(wsrc + (((j << 8) + t) << 3));
        *(uint4*)((char*)wbuf + (((j << 8) + t) << 4)) = v;
      }
    }
    __syncthreads();   // wbuf ready

    f32x4 acc1[4][2];
    #pragma unroll
    for (int ct = 0; ct < 4; ++ct)
      #pragma unroll
      for (int pt = 0; pt < 2; ++pt) acc1[ct][pt] = (f32x4){0.f, 0.f, 0.f, 0.f};
    #pragma unroll
    for (int ks = 0; ks < 4; ++ks) {
      bf16x8 xf[2];
      #pragma unroll
      for (int pt = 0; pt < 2; ++pt) {
        int pix = pxw + (pt << 4) + cl;
        int e = (pix * 256 + ks * 64 + g * 16) ^ swz;
        xf[pt] = *(const bf16x8*)((const char*)xs + e);
      }
      #pragma unroll
      for (int ct = 0; ct < 4; ++ct) {
        bf16x8 wf = *(const bf16x8*)((const char*)wbuf + (((ks << 2) + ct) << 10) + (l << 4));
        acc1[ct][0] = __builtin_amdgcn_mfma_f32_16x16x32_bf16(wf, xf[0], acc1[ct][0], 0, 0, 0);
        acc1[ct][1] = __builtin_amdgcn_mfma_f32_16x16x32_bf16(wf, xf[1], acc1[ct][1], 0, 0, 0);
      }
    }

    #pragma unroll
    for (int pt = 0; pt < 2; ++pt) {
      int pix = pxw + (pt << 4) + cl;
      float rv = rncol[pt];
      #pragma unroll
      for (int ct = 0; ct < 4; ++ct) {
        float4 mb4 = *(const float4*)&mbL[n0 + (ct << 4) + (g << 2)];
        f32x4 a = acc1[ct][pt];
        float m[4];
        #pragma unroll
        for (int r = 0; r < 4; ++r) {
          float z = a[r] * rv + ((const float*)&mb4)[r];
          m[r] = __builtin_amdgcn_rcpf(1.f + __expf(-z));
        }
        u32 lo, hi;
        asm("v_cvt_pk_bf16_f32 %0, %1, %2" : "=v"(lo) : "v"(m[0]), "v"(m[1]));
        asm("v_cvt_pk_bf16_f32 %0, %1, %2" : "=v"(hi) : "v"(m[2]), "v"(m[3]));
        int e = (pix * 128 + ct * 32 + g * 8) ^ swz;
        uint2 st = { lo, hi };
        *(uint2*)((char*)modL + e) = st;
      }
    }

    #pragma unroll
    for (int kt = 0; kt < 2; ++kt) {
      bf16x8 af[2];
      #pragma unroll
      for (int pt = 0; pt < 2; ++pt) {
        int pix = pxw + (pt << 4) + cl;
        int e = (pix * 128 + kt * 64 + g * 16) ^ swz;
        af[pt] = *(const bf16x8*)((const char*)modL + e);
      }
      #pragma unroll
      for (int nt = 0; nt < 4; ++nt) {
        bf16x8 bfr = *(const bf16x8*)((const char*)wbuf + 16384 + (((kt << 2) + nt) << 10) + (l << 4));
        acc2[0][nt] = __builtin_amdgcn_mfma_f32_16x16x32_bf16(af[0], bfr, acc2[0][nt], 0, 0, 0);
        acc2[1][nt] = __builtin_amdgcn_mfma_f32_16x16x32_bf16(af[1], bfr, acc2[1][nt], 0, 0, 0);
      }
    }
  }

  // GEMM3: Sc = (x @ c2F^T) * rn
  f32x4 acc3[2][4];
  #pragma unroll
  for (int pt = 0; pt < 2; ++pt)
    #pragma unroll
    for (int nt = 0; nt < 4; ++nt) acc3[pt][nt] = (f32x4){0.f, 0.f, 0.f, 0.f};
  #pragma unroll
  for (int ks = 0; ks < 4; ++ks) {
    bf16x8 af[2];
    #pragma unroll
    for (int pt = 0; pt < 2; ++pt) {
      int pix = pxw + (pt << 4) + cl;
      int e = (pix * 256 + ks * 64 + g * 16) ^ swz;
      af[pt] = *(const bf16x8*)((const char*)xs + e);
    }
    #pragma unroll
    for (int nt = 0; nt < 4; ++nt) {
      bf16x8 bfr = *(const bf16x8*)&c2F[(size_t)((nt << 4) + cl) * 128 + ks * 32 + g * 8];
      acc3[0][nt] = __builtin_amdgcn_mfma_f32_16x16x32_bf16(af[0], bfr, acc3[0][nt], 0, 0, 0);
      acc3[1][nt] = __builtin_amdgcn_mfma_f32_16x16x32_bf16(af[1], bfr, acc3[1][nt], 0, 0, 0);
    }
  }

  // epilogue -> Snp[patch][k'], k' = p*512 + c*4 + q (bf16), p = y&3 fixed
  const int pgrp = (b << 5) + (y >> 2);
  u16* Srow = Snp + ((size_t)pgrp << 16) + ((y & 3) << 9);
  #pragma unroll
  for (int pt = 0; pt < 2; ++pt) {
    int pixr = pxw + (pt << 4) + (g << 2);
    float4 rn4 = *(const float4*)&rn[pixr];
    int pw = pixr >> 2;
    #pragma unroll
    for (int nt = 0; nt < 4; ++nt) {
      int c = (nt << 4) + cl;
      float b1 = conv1_b[c];
      f32x4 a2 = acc2[pt][nt];
      uint2 s0 = { pk2(a2[0] + b1, a2[1] + b1), pk2(a2[2] + b1, a2[3] + b1) };
      *(uint2*)&Srow[((size_t)pw << 11) + (c << 2)] = s0;
      float b2 = conv2_b[c];
      f32x4 a3 = acc3[pt][nt];
      uint2 s1v = { pk2(a3[0] * rn4.x + b2, a3[1] * rn4.y + b2),
                    pk2(a3[2] * rn4.z + b2, a3[3] * rn4.w + b2) };
      *(uint2*)&Srow[((size_t)pw << 11) + ((c + 64) << 2)] = s1v;
    }
  }
}

// ------- kernel BC: fused PatchEmbed GEMM + LN -> (LDS) -> PatchExpand ------
// 512 threads / 8 waves: phase-1 each wave owns ONE 16-chan n-tile; phase-3
// jt = w*4+jj; phase-4 pixl = (w*2+mt4)*16+cl. LDS identical to 4-wave build.
__global__ __launch_bounds__(512) void k_pe_ex(
    const u16* __restrict__ Snp, const u16* __restrict__ pewB,
    const float* __restrict__ pe_b, const float* __restrict__ pe_g,
    const float* __restrict__ pe_beta,
    const u16* __restrict__ expB,
    const float* __restrict__ fin_g, const float* __restrict__ fin_b,
    const u16* __restrict__ upF, const float* __restrict__ up_b,
    u16* __restrict__ M1b)
{
  __shared__ u16 As[8192];        // 16 patches x 512 k, XOR-swizzled (16KB)
  __shared__ float fln[16][132];  // 8.25KB
  __shared__ u16 fb[2048];        // [16 patches][128] bf16, XOR (p&7)<<4 (4KB)
  __shared__ u16 feL[8192];       // (16KB)
  __shared__ u16 feL2[8192];      // (16KB)
  __shared__ float lng[32], lnb[32];
  const int t = threadIdx.x, bx = blockIdx.x;
  const int w = t >> 6, l = t & 63;
  const int g = l >> 4, cl = l & 15;
  const size_t gbase = (size_t)bx << 15;
  const int pg0 = bx << 4;

  if (t < 32) { lng[t] = fin_g[t]; lnb[t] = fin_b[t]; }

  // ---------------- phase 1: PatchEmbed GEMM (M=16, N=128, K=2048) ---------
  // wave w computes n-tile w (16 output chans) for all 16 patches.
  f32x4 acc = (f32x4){0.f, 0.f, 0.f, 0.f};

  for (int chunk = 0; chunk < 4; ++chunk) {
    __syncthreads();
    #pragma unroll
    for (int it = 0; it < 2; ++it) {
      int e8 = ((it << 9) + t) << 3;       // 1024 x 16B total
      int pl = e8 >> 9, kk = e8 & 511;
      uint4 v = *(const uint4*)&Snp[gbase + ((size_t)pl << 11) + (chunk << 9) + kk];
      int e = (((pl << 9) + kk) << 1) ^ ((pl & 7) << 4);
      *(uint4*)((char*)As + e) = v;
    }
    __syncthreads();
    for (int ks = 0; ks < 16; ++ks) {
      int kk = (ks << 5) + (g << 3);
      int e = (((cl << 9) + kk) << 1) ^ ((cl & 7) << 4);
      bf16x8 A = *(const bf16x8*)((const char*)As + e);
      int gks = (chunk << 4) + ks;
      bf16x8 B = *(const bf16x8*)&pewB[(size_t)((((gks << 3) + w) << 6) + l) << 3];
      acc = __builtin_amdgcn_mfma_f32_16x16x32_bf16(A, B, acc, 0, 0, 0);
    }
  }

  {
    int o = (w << 4) + cl;
    float pb = pe_b[o];
    #pragma unroll
    for (int r = 0; r < 4; ++r)
      fln[(g << 2) + r][o] = acc[r] + pb;
  }
  __syncthreads();

  // ------------- phase 2: LN over 128 chans -> fb (LDS, bf16) -------------
  if (t < 128) {
    int patch = t >> 3, sub = t & 7;
    float4 v0 = *(const float4*)&fln[patch][(sub << 4) + 0];
    float4 v1 = *(const float4*)&fln[patch][(sub << 4) + 4];
    float4 v2 = *(const float4*)&fln[patch][(sub << 4) + 8];
    float4 v3 = *(const float4*)&fln[patch][(sub << 4) + 12];
    float s1 = v0.x + v0.y + v0.z + v0.w + v1.x + v1.y + v1.z + v1.w
             + v2.x + v2.y + v2.z + v2.w + v3.x + v3.y + v3.z + v3.w;
    float s2 = v0.x*v0.x + v0.y*v0.y + v0.z*v0.z + v0.w*v0.w
             + v1.x*v1.x + v1.y*v1.y + v1.z*v1.z + v1.w*v1.w
             + v2.x*v2.x + v2.y*v2.y + v2.z*v2.z + v2.w*v2.w
             + v3.x*v3.x + v3.y*v3.y + v3.z*v3.z + v3.w*v3.w;
    s1 += __shfl_xor(s1, 1); s2 += __shfl_xor(s2, 1);
    s1 += __shfl_xor(s1, 2); s2 += __shfl_xor(s2, 2);
    s1 += __shfl_xor(s1, 4); s2 += __shfl_xor(s2, 4);
    float m = s1 * (1.f / 128.f);
    float var = s2 * (1.f / 128.f) - m * m;
    float rs = rsqrtf(var + 1e-5f);
    int o0 = sub << 4;
    #pragma unroll
    for (int i = 0; i < 4; ++i) {
      float4 vv = (i == 0) ? v0 : (i == 1) ? v1 : (i == 2) ? v2 : v3;
      float4 gv = *(const float4*)&pe_g[o0 + (i << 2)];
      float4 bv = *(const float4*)&pe_beta[o0 + (i << 2)];
      uint2 st = { pk2((vv.x - m) * rs * gv.x + bv.x, (vv.y - m) * rs * gv.y + bv.y),
                   pk2((vv.z - m) * rs * gv.z + bv.z, (vv.w - m) * rs * gv.w + bv.w) };
      int c = o0 + (i << 2);
      int e = (patch * 256 + c * 2) ^ ((patch & 7) << 4);
      *(uint2*)((char*)fb + e) = st;
    }
  }
  __syncthreads();

  // ------------- phase 3: PatchExpand GEMM (swapped) + LN(32) -------------
  // wave w: jt = w*4 + jj, jj < 4  (32 jt tiles over 8 waves)
  f32x4 acc1[4];
  #pragma unroll
  for (int jj = 0; jj < 4; ++jj) acc1[jj] = (f32x4){0.f, 0.f, 0.f, 0.f};
  #pragma unroll
  for (int ks = 0; ks < 4; ++ks) {
    int e = (cl * 256 + ks * 64 + g * 16) ^ ((cl & 7) << 4);
    bf16x8 ff = *(const bf16x8*)((const char*)fb + e);
    #pragma unroll
    for (int jj = 0; jj < 4; ++jj) {
      int jt = (w << 2) + jj;
      bf16x8 wf = *(const bf16x8*)&expB[(size_t)((jt << 4) + cl) * 128 + ks * 32 + g * 8];
      acc1[jj] = __builtin_amdgcn_mfma_f32_16x16x32_bf16(wf, ff, acc1[jj], 0, 0, 0);
    }
  }
  // store: lane -> patch = cl, j0 = jt*16 + g*4 (4 consecutive j as bf16)
  #pragma unroll
  for (int jj = 0; jj < 4; ++jj) {
    int j0 = (((w << 2) + jj) << 4) + (g << 2);
    f32x4 a = acc1[jj];
    uint2 st = { pk2(a[0], a[1]), pk2(a[2], a[3]) };
    int e = (cl * 1024 + j0 * 2) ^ ((cl & 7) << 3);
    *(uint2*)((char*)feL + e) = st;
  }
  __syncthreads();

  if (t < 256) { // LN over 32-chan groups; thread t -> pixel t
    int patch = t >> 4, sub = t & 15;
    int rot = t & 15;
    int baseR = patch * 1024 + sub * 64;
    int xr = (patch & 7) << 3;
    float vals[32];
    float s1 = 0.f, s2 = 0.f;
    #pragma unroll
    for (int wd = 0; wd < 16; ++wd) {
      int ww = (wd + rot) & 15;
      u32 u = *(const u32*)((const char*)feL + ((baseR + ww * 4) ^ xr));
      float lo, hi; up2(u, lo, hi);
      vals[wd * 2] = lo; vals[wd * 2 + 1] = hi;
      s1 += lo + hi; s2 += lo * lo + hi * hi;
    }
    float m = s1 * (1.f / 32.f);
    float var = s2 * (1.f / 32.f) - m * m;
    float rs = rsqrtf(var + 1e-5f);
    int baseW = t * 64;
    int xw = (t & 3) << 4;           // 16B-granularity XOR
    #pragma unroll
    for (int wd = 0; wd < 16; ++wd) {
      int ww = (wd + rot) & 15;
      float lo = (vals[wd * 2]     - m) * rs * lng[ww * 2]     + lnb[ww * 2];
      float hi = (vals[wd * 2 + 1] - m) * rs * lng[ww * 2 + 1] + lnb[ww * 2 + 1];
      *(u32*)((char*)feL2 + ((baseW + ww * 4) ^ xw)) = pk2(lo, hi);
    }
  }
  __syncthreads();

  // up-proj (swapped): wave w handles pixl half-tiles (w*2+mt4), mt4 < 2.
  #pragma unroll
  for (int mt4 = 0; mt4 < 2; ++mt4) {
    int pixl = (((w << 1) + mt4) << 4) + cl;
    int e = (pixl * 64 + g * 16) ^ ((pixl & 3) << 4);
    bf16x8 fef = *(const bf16x8*)((const char*)feL2 + e);
    int pglob = pg0 + (pixl >> 4);
    int sub = pixl & 15;
    int bb = pglob >> 10, ph = (pglob >> 5) & 31, pw = pglob & 31;
    int yy = (ph << 2) + (sub >> 2), xx = (pw << 2) + (sub & 3);
    size_t mbase = ((size_t)(((bb << 7) + yy) << 7) + xx) << 7;
    f32x4 accu[8];
    #pragma unroll
    for (int nt = 0; nt < 8; ++nt) {
      bf16x8 wfu = *(const bf16x8*)&upF[((nt << 4) + cl) * 32 + g * 8];
      accu[nt] = __builtin_amdgcn_mfma_f32_16x16x32_bf16(
          wfu, fef, (f32x4){0.f, 0.f, 0.f, 0.f}, 0, 0, 0);
    }
    #pragma unroll
    for (int nt = 0; nt < 8; ++nt) {
      int o0 = (nt << 4) + (g << 2);
      float4 ub4 = *(const float4*)&up_b[o0];
      f32x4 a = accu[nt];
      uint2 st = { pk2(a[0] + ub4.x, a[1] + ub4.y),
                   pk2(a[2] + ub4.z, a[3] + ub4.w) };
      *(uint2*)&M1b[mbase + o0] = st;
    }
  }
}

// ---------------- kernel D: Xn = fwt0*(query@Wpre^T) + fwt1*M1b, MFMA -------
__global__ __launch_bounds__(256) void k_wf(
    const float* __restrict__ Q, const u16* __restrict__ wpreF,
    const u16* __restrict__ M1b, const float* __restrict__ w2,
    u16* __restrict__ Xn)
{
  __shared__ u16 qs[16384];   // [pix=128][c=128] bf16, XOR-swizzled
  const int t = threadIdx.x;
  const int b = blockIdx.x >> 7;
  const int hw0 = (blockIdx.x & 127) << 7;

  { // stage query row (bf16, swizzled)
    const int pix = t & 127, ch = t >> 7;
    const float* Qp = Q + ((size_t)b << 21) + (size_t)hw0 + pix;
    #pragma unroll
    for (int c0 = 0; c0 < 64; c0 += 8) {
      float v[8]; u32 pkv[4];
      #pragma unroll
      for (int j = 0; j < 8; ++j)
        v[j] = Qp[(size_t)(ch * 64 + c0 + j) << 14];
      #pragma unroll
      for (int j = 0; j < 4; ++j) pkv[j] = pk2(v[2 * j], v[2 * j + 1]);
      int e = pix * 256 + (ch * 64 + c0) * 2;
      e ^= (pix & 7) << 4;
      *(uint4*)((char*)qs + e) = *(const uint4*)pkv;
    }
  }
  __syncthreads();

  const int w = t >> 6, l = t & 63;
  const int g = l >> 4, cl = l & 15;
  const int pxw = w << 5;
  const int swz = (cl & 7) << 4;

  f32x4 acc[2][8];
  #pragma unroll
  for (int pt = 0; pt < 2; ++pt)
    #pragma unroll
    for (int ot = 0; ot < 8; ++ot) acc[pt][ot] = (f32x4){0.f, 0.f, 0.f, 0.f};

  #pragma unroll
  for (int ks = 0; ks < 4; ++ks) {
    bf16x8 qf[2];
    #pragma unroll
    for (int pt = 0; pt < 2; ++pt) {
      int pix = pxw + (pt << 4) + cl;
      int e = (pix * 256 + ks * 64 + g * 16) ^ swz;
      qf[pt] = *(const bf16x8*)((const char*)qs + e);
    }
    #pragma unroll
    for (int ot = 0; ot < 8; ++ot) {
      bf16x8 wf = *(const bf16x8*)&wpreF[(size_t)((ot << 4) + cl) * 128 + ks * 32 + g * 8];
      acc[0][ot] = __builtin_amdgcn_mfma_f32_16x16x32_bf16(wf, qf[0], acc[0][ot], 0, 0, 0);
      acc[1][ot] = __builtin_amdgcn_mfma_f32_16x16x32_bf16(wf, qf[1], acc[1][ot], 0, 0, 0);
    }
  }

  float a0 = fmaxf(w2[0], 0.f), a1 = fmaxf(w2[1], 0.f);
  float inv = 1.f / (a0 + a1 + 1e-8f);
  float f0 = a0 * inv, f1 = a1 * inv;

  #pragma unroll
  for (int pt = 0; pt < 2; ++pt) {
    int pix = pxw + (pt << 4) + cl;
    size_t pbase = ((size_t)((b << 14) + hw0 + pix)) << 7;
    #pragma unroll
    for (int ot = 0; ot < 8; ++ot) {
      int o0 = (ot << 4) + (g << 2);
      uint2 mv = *(const uint2*)&M1b[pbase + o0];
      float m0, m1, m2, m3;
      up2(mv.x, m0, m1); up2(mv.y, m2, m3);
      f32x4 a = acc[pt][ot];
      uint2 st = { pk2(f0 * a[0] + f1 * m0, f0 * a[1] + f1 * m1),
                   pk2(f0 * a[2] + f1 * m2, f0 * a[3] + f1 * m3) };
      *(uint2*)&Xn[pbase + o0] = st;
    }
  }
}

// ---------------- kernel E: 3x3 conv (MFMA implicit GEMM) + BN + ReLU6 ------
// 6-tap phases: 48KB wb, 6 phases x 2 barriers = 12 barriers.
__global__ __launch_bounds__(256) void k_conv3(
    const u16* __restrict__ Xn, const u16* __restrict__ wpk,
    const float* __restrict__ bnb, float* __restrict__ out)
{
  __shared__ u16 it[12800];    // 100 rows x 128 ic, XOR-swizzled (25.6KB)
  __shared__ u16 wb[24576];    // 6 taps x 8 n x 64 lanes x 8 e (48KB)
  const int t = threadIdx.x, bx = blockIdx.x;
  const int b = bx >> 8, rem = bx & 255;
  const int ty8 = (rem >> 4) << 3, tx8 = (rem & 15) << 3;
  const int y0 = ty8 - 1, x0 = tx8 - 1;

  for (int idx = t; idx < 1600; idx += 256) {
    int ri = idx >> 4, cc = idx & 15;
    int gy = y0 + ri / 10, gx = x0 + ri % 10;
    uint4 v = {0u, 0u, 0u, 0u};
    if (gy >= 0 && gy < 128 && gx >= 0 && gx < 128)
      v = *(const uint4*)&Xn[(((size_t)(b << 14) + (gy << 7) + gx) << 7) + (cc << 3)];
    int e = (ri << 7) + (cc << 3);
    e ^= (ri & 7) << 3;
    *(uint4*)&it[e] = v;
  }

  const int w = t >> 6, l = t & 63;
  const int g = l >> 4, cl = l & 15;

  f32x4 acc[4][2];
  #pragma unroll
  for (int m = 0; m < 4; ++m)
    #pragma unroll
    for (int nn = 0; nn < 2; ++nn)
      acc[m][nn] = (f32x4){0.f, 0.f, 0.f, 0.f};

  int ri0[4];
  #pragma unroll
  for (int m = 0; m < 4; ++m) {
    int p = (m << 4) + cl;
    ri0[m] = (p >> 3) * 10 + (p & 7);
  }

  #pragma unroll
  for (int p = 0; p < 6; ++p) {
    __syncthreads();   // prior phase's wb reads (and initial it stage) done
    { // stage 6 taps of B fragments: contiguous 48KB from wpk (12/thread)
      const u16* wsrc = wpk + p * 24576;
      #pragma unroll
      for (int j = 0; j < 12; ++j) {
        uint4 v = *(const uint4*)(wsrc + (((j << 8) + t) << 3));
        *(uint4*)((char*)wb + (((j << 8) + t) << 4)) = v;
      }
    }
    __syncthreads();   // wb ready (also covers it on first pass)

    #pragma unroll
    for (int tl = 0; tl < 6; ++tl) {
      const int q = p * 6 + tl;            // global (ks,tap) index 0..35
      const int ks = q / 9, tap = q % 9;
      const int dy = tap / 3, dx = tap % 3;
      bf16x8 A[4];
      #pragma unroll
      for (int m = 0; m < 4; ++m) {
        int ri = ri0[m] + dy * 10 + dx;
        int e = (ri << 7) + (ks << 5) + (g << 3);
        e ^= (ri & 7) << 3;
        A[m] = *(const bf16x8*)&it[e];
      }
      #pragma unroll
      for (int nn = 0; nn < 2; ++nn) {
        int n = (w << 1) + nn;
        bf16x8 B = *(const bf16x8*)((const char*)wb + (((tl << 3) + n) << 10) + (l << 4));
        #pragma unroll
        for (int m = 0; m < 4; ++m)
          acc[m][nn] = __builtin_amdgcn_mfma_f32_16x16x32_bf16(A[m], B, acc[m][nn], 0, 0, 0);
      }
    }
  }

  #pragma unroll
  for (int m = 0; m < 4; ++m) {
    int p = (m << 4) + (g << 2);
    int py = p >> 3, px = p & 7;
    #pragma unroll
    for (int nn = 0; nn < 2; ++nn) {
      int n = (w << 1) + nn;
      int o = (n << 4) + cl;
      float bb = bnb[o];
      f32x4 a = acc[m][nn];
      float4 v = { fminf(fmaxf(a[0] + bb, 0.f), 6.f),
                   fminf(fmaxf(a[1] + bb, 0.f), 6.f),
                   fminf(fmaxf(a[2] + bb, 0.f), 6.f),
                   fminf(fmaxf(a[3] + bb, 0.f), 6.f) };
      *(float4*)&out[((size_t)((b << 7) + o) << 14) + ((ty8 + py) << 7) + tx8 + px] = v;
    }
  }
}

extern "C" void kernel_launch(void* const* d_in, const int* in_sizes, int n_in,
                              void* d_out, int out_size, void* d_ws, size_t ws_size,
                              hipStream_t stream) {
  const float* Structure = (const float*)d_in[0];
  const float* query     = (const float*)d_in[1];
  const float* m_items   = (const float*)d_in[2];
  const float* mod_w     = (const float*)d_in[3];
  const float* mod_b     = (const float*)d_in[4];
  const float* conv1_w   = (const float*)d_in[5];
  const float* conv1_b   = (const float*)d_in[6];
  const float* conv2_w   = (const float*)d_in[7];
  const float* conv2_b   = (const float*)d_in[8];
  const float* pe_w      = (const float*)d_in[9];
  const float* pe_b      = (const float*)d_in[10];
  const float* pe_g      = (const float*)d_in[11];
  const float* pe_beta   = (const float*)d_in[12];
  const float* exp_w     = (const float*)d_in[13];
  const float* fin_g     = (const float*)d_in[14];
  const float* fin_b     = (const float*)d_in[15];
  const float* up_w      = (const float*)d_in[16];
  const float* up_b      = (const float*)d_in[17];
  const float* wf_w2     = (const float*)d_in[18];
  const float* wf_pre_w  = (const float*)d_in[19];
  const float* wf_post_w = (const float*)d_in[20];
  const float* wf_bn_g   = (const float*)d_in[21];
  const float* wf_bn_b   = (const float*)d_in[22];

  char* ws = (char*)d_ws;
  u16*   Snp = (u16*)(ws + 0);               // 16,777,216 B (bf16 im2col, k')
  u16*   expB = (u16*)(ws + 34603008);       //    131,072 B
  u16*   upF  = (u16*)(ws + 34734080);       //      8,192 B
  u16*   M1b = (u16*)(ws + 35651584);        // 16,777,216 B (bf16 NHWC)
  u16*   Xn  = (u16*)(ws + 0);               // alias Snp (dead after k_pe_ex)
  u16* wcomb = (u16*)(ws + 69206016);        // 245,760 B
  u16* c2F   = (u16*)(ws + 69451776);        //  16,384 B
  u16* wpreF = (u16*)(ws + 69468160);        //  32,768 B
  u16* wpk   = (u16*)(ws + 69500928);        // 294,912 B
  u16* pewB  = (u16*)(ws + 69795840);        // 524,288 B -> end 70,320,128 B

  k_prep<<<2448, 256, 0, stream>>>(mod_w, conv1_w, m_items, conv2_w, wf_pre_w,
                                   wf_post_w, wf_bn_g, pe_w, exp_w, up_w,
                                   wcomb, c2F, wpreF, wpk, pewB, expB, upF);
  k_read<<<512, 256, 0, stream>>>(Structure, wcomb, c2F, mod_b,
                                  conv1_b, conv2_b, Snp);
  k_pe_ex<<<256, 512, 0, stream>>>(Snp, pewB, pe_b, pe_g, pe_beta,
                                   expB, fin_g, fin_b, upF, up_b, M1b);
  k_wf<<<512, 256, 0, stream>>>(query, wpreF, M1b, wf_w2, Xn);
  k_conv3<<<1024, 256, 0, stream>>>(Xn, wpk, wf_bn_b, (float*)d_out);
}

// Round 28
// 123.967 us; speedup vs baseline: 1.2152x; 1.0039x over previous
//
#include <hip/hip_runtime.h>

typedef unsigned short u16;
typedef unsigned int u32;
typedef __attribute__((ext_vector_type(8))) short bf16x8;
typedef __attribute__((ext_vector_type(4))) float f32x4;

__device__ __forceinline__ float b2f(u16 h) {
  union { u32 u; float f; } v; v.u = ((u32)h) << 16; return v.f;
}
__device__ __forceinline__ u16 f2b(float x) {
  union { float f; u32 u; } v; v.f = x;
  u32 u = v.u;
  return (u16)((u + 0x7FFFu + ((u >> 16) & 1u)) >> 16);  // RTN-even
}
__device__ __forceinline__ void up2(u32 u, float& lo, float& hi) {
  union { u32 x; float f; } a, b;
  a.x = u << 16; b.x = u & 0xFFFF0000u;
  lo = a.f; hi = b.f;
}
__device__ __forceinline__ u32 pk2(float lo, float hi) {
  return (u32)f2b(lo) | ((u32)f2b(hi) << 16);
}

// ---------------- prep: weight transposes / folds (bf16) ----------------
// wcomb: 10 chunks x 12288 u16 (GEMM1 A-frags + GEMM2 B-frags, frag order)
// wpk:  conv3 weights, contiguous per (ks,tap): 8KB fragment blobs
__global__ __launch_bounds__(256) void k_prep(
    const float* __restrict__ mod_w, const float* __restrict__ conv1_w,
    const float* __restrict__ m_items, const float* __restrict__ conv2_w,
    const float* __restrict__ wf_pre_w, const float* __restrict__ wf_post_w,
    const float* __restrict__ wf_bn_g, const float* __restrict__ pe_w,
    const float* __restrict__ exp_w, const float* __restrict__ up_w,
    u16* __restrict__ wcomb, u16* __restrict__ c2F,
    u16* __restrict__ wpreF, u16* __restrict__ wpk, u16* __restrict__ pewB,
    u16* __restrict__ expB, u16* __restrict__ upF)
{
  int idx = blockIdx.x * 256 + threadIdx.x;
  if (idx < 122880) {
    int chunk = idx / 12288, r = idx % 12288;
    float val;
    if (r < 8192) {
      int e = r & 7, lane = (r >> 3) & 63, fr = r >> 9;   // fr 0..15
      int ks = fr >> 2, ct = fr & 3;
      int chan = chunk * 64 + ct * 16 + (lane & 15);
      int c = ks * 32 + ((lane >> 4) << 3) + e;
      val = mod_w[chan * 128 + c];
    } else {
      int r2 = r - 8192;
      int e = r2 & 7, lane = (r2 >> 3) & 63, fr = r2 >> 9; // fr 0..7
      int kt = fr >> 2, nt = fr & 3;
      int o = nt * 16 + (lane & 15);
      int k = chunk * 64 + kt * 32 + ((lane >> 4) << 3) + e;
      val = conv1_w[o * 640 + k] * m_items[k];
    }
    wcomb[idx] = f2b(val);
  } else if (idx < 131072) {
    int i = idx - 122880;
    c2F[i] = f2b(conv2_w[i]);
  } else if (idx < 147456) {
    int i = idx - 131072;
    wpreF[i] = f2b(wf_pre_w[i]);
  } else if (idx < 294912) {
    int i2 = idx - 147456;
    int e = i2 & 7;
    int r = i2 >> 3;
    int lane = r & 63; r >>= 6;
    int n = r & 7; r >>= 3;          // r = ks*9+tap, 0..35
    int tap = r % 9, ks = r / 9;
    int o = (n << 4) + (lane & 15);
    int ic = (ks << 5) + ((lane >> 4) << 3) + e;
    int dy = tap / 3, dx = tap % 3;
    float scale = wf_bn_g[o] * rsqrtf(1.f + 1e-5f);
    wpk[i2] = f2b(wf_post_w[((o * 128 + ic) * 3 + dy) * 3 + dx] * scale);
  } else if (idx < 557056) {
    int i = idx - 294912;            // 0..262143
    int e = i & 7;
    int r = i >> 3;
    int lane = r & 63; r >>= 6;
    int n = r & 7;
    int gks = r >> 3;                // 0..63
    int o = (n << 4) + (lane & 15);
    int kp = (gks << 5) + ((lane >> 4) << 3) + e;   // k' index
    int p = kp >> 9, c = (kp >> 2) & 127, q = kp & 3;
    int k = c * 16 + p * 4 + q;
    pewB[i] = f2b(pe_w[o * 2048 + k]);
  } else if (idx < 622592) {
    int i = idx - 557056;            // 0..65535
    int j = i >> 7, c = i & 127;
    expB[i] = f2b(exp_w[c * 512 + j]);
  } else if (idx < 626688) {
    int i = idx - 622592;            // 0..4095
    upF[i] = f2b(up_w[i]);
  }
}

// ---------------- kernel A: fused read() -> Snp [4096 patches][2048] bf16 ---
__global__ __launch_bounds__(256) void k_read(
    const float* __restrict__ S, const u16* __restrict__ wcomb,
    const u16* __restrict__ c2F,
    const float* __restrict__ mod_b,
    const float* __restrict__ conv1_b, const float* __restrict__ conv2_b,
    u16* __restrict__ Snp)
{
  __shared__ u16 xs[16384];        // [pix=128][c=128] bf16, XOR-swizzled (32KB)
  __shared__ u16 modL[8192];       // [pix=128][kk=64] bf16, XOR-swizzled (16KB)
  __shared__ u16 wbuf[12288];      // staged weight fragments (24KB)
  __shared__ float rn[128];
  __shared__ float ps[2][128];
  __shared__ float mbL[640];

  const int t = threadIdx.x;
  const int b = blockIdx.x >> 7;
  const int y = blockIdx.x & 127;
  const int hw0 = y << 7;

  { // stage x (unnormalized bf16) + sumsq
    const int pix = t & 127, ch = t >> 7;
    const float* Sp = S + ((size_t)b << 21) + (size_t)hw0 + pix;
    float ss = 0.f;
    #pragma unroll
    for (int c0 = 0; c0 < 64; c0 += 8) {
      float v[8]; u32 pkv[4];
      #pragma unroll
      for (int j = 0; j < 8; ++j) {
        v[j] = Sp[(size_t)(ch * 64 + c0 + j) << 14];
        ss += v[j] * v[j];
      }
      #pragma unroll
      for (int j = 0; j < 4; ++j) pkv[j] = pk2(v[2 * j], v[2 * j + 1]);
      int e = pix * 256 + (ch * 64 + c0) * 2;
      e ^= (pix & 7) << 4;
      *(uint4*)((char*)xs + e) = *(const uint4*)pkv;
    }
    ps[ch][pix] = ss;
  }
  for (int i = t; i < 640; i += 256) mbL[i] = mod_b[i];
  __syncthreads();
  if (t < 128) rn[t] = 1.f / fmaxf(sqrtf(ps[0][t] + ps[1][t]), 1e-12f);

  const int w = t >> 6, l = t & 63;
  const int g = l >> 4, cl = l & 15;
  const int pxw = w << 5;
  const int swz = (cl & 7) << 4;

  __syncthreads();
  float rncol[2] = { rn[pxw + cl], rn[pxw + 16 + cl] };

  f32x4 acc2[2][4];
  #pragma unroll
  for (int pt = 0; pt < 2; ++pt)
    #pragma unroll
    for (int nt = 0; nt < 4; ++nt) acc2[pt][nt] = (f32x4){0.f, 0.f, 0.f, 0.f};

  for (int i = 0; i < 10; ++i) {
    const int n0 = i << 6;
    __syncthreads();   // prior iteration's wbuf reads complete
    {
      const u16* wsrc = wcomb + i * 12288;
      #pragma unroll
      for (int j = 0; j < 6; ++j) {
        uint4 v = *(const uint4*)(wsrc + (((j << 8) + t) << 3));
        *(uint4*)((char*)wbuf + (((j << 8) + t) << 4)) = v;
      }
    }
    __syncthreads();   // wbuf ready

    f32x4 acc1[4][2];
    #pragma unroll
    for (int ct = 0; ct < 4; ++ct)
      #pragma unroll
      for (int pt = 0; pt < 2; ++pt) acc1[ct][pt] = (f32x4){0.f, 0.f, 0.f, 0.f};
    #pragma unroll
    for (int ks = 0; ks < 4; ++ks) {
      bf16x8 xf[2];
      #pragma unroll
      for (int pt = 0; pt < 2; ++pt) {
        int pix = pxw + (pt << 4) + cl;
        int e = (pix * 256 + ks * 64 + g * 16) ^ swz;
        xf[pt] = *(const bf16x8*)((const char*)xs + e);
      }
      #pragma unroll
      for (int ct = 0; ct < 4; ++ct) {
        bf16x8 wf = *(const bf16x8*)((const char*)wbuf + (((ks << 2) + ct) << 10) + (l << 4));
        acc1[ct][0] = __builtin_amdgcn_mfma_f32_16x16x32_bf16(wf, xf[0], acc1[ct][0], 0, 0, 0);
        acc1[ct][1] = __builtin_amdgcn_mfma_f32_16x16x32_bf16(wf, xf[1], acc1[ct][1], 0, 0, 0);
      }
    }

    #pragma unroll
    for (int pt = 0; pt < 2; ++pt) {
      int pix = pxw + (pt << 4) + cl;
      float rv = rncol[pt];
      #pragma unroll
      for (int ct = 0; ct < 4; ++ct) {
        float4 mb4 = *(const float4*)&mbL[n0 + (ct << 4) + (g << 2)];
        f32x4 a = acc1[ct][pt];
        float m[4];
        #pragma unroll
        for (int r = 0; r < 4; ++r) {
          float z = a[r] * rv + ((const float*)&mb4)[r];
          m[r] = __builtin_amdgcn_rcpf(1.f + __expf(-z));
        }
        u32 lo, hi;
        asm("v_cvt_pk_bf16_f32 %0, %1, %2" : "=v"(lo) : "v"(m[0]), "v"(m[1]));
        asm("v_cvt_pk_bf16_f32 %0, %1, %2" : "=v"(hi) : "v"(m[2]), "v"(m[3]));
        int e = (pix * 128 + ct * 32 + g * 8) ^ swz;
        uint2 st = { lo, hi };
        *(uint2*)((char*)modL + e) = st;
      }
    }

    #pragma unroll
    for (int kt = 0; kt < 2; ++kt) {
      bf16x8 af[2];
      #pragma unroll
      for (int pt = 0; pt < 2; ++pt) {
        int pix = pxw + (pt << 4) + cl;
        int e = (pix * 128 + kt * 64 + g * 16) ^ swz;
        af[pt] = *(const bf16x8*)((const char*)modL + e);
      }
      #pragma unroll
      for (int nt = 0; nt < 4; ++nt) {
        bf16x8 bfr = *(const bf16x8*)((const char*)wbuf + 16384 + (((kt << 2) + nt) << 10) + (l << 4));
        acc2[0][nt] = __builtin_amdgcn_mfma_f32_16x16x32_bf16(af[0], bfr, acc2[0][nt], 0, 0, 0);
        acc2[1][nt] = __builtin_amdgcn_mfma_f32_16x16x32_bf16(af[1], bfr, acc2[1][nt], 0, 0, 0);
      }
    }
  }

  // GEMM3: Sc = (x @ c2F^T) * rn
  f32x4 acc3[2][4];
  #pragma unroll
  for (int pt = 0; pt < 2; ++pt)
    #pragma unroll
    for (int nt = 0; nt < 4; ++nt) acc3[pt][nt] = (f32x4){0.f, 0.f, 0.f, 0.f};
  #pragma unroll
  for (int ks = 0; ks < 4; ++ks) {
    bf16x8 af[2];
    #pragma unroll
    for (int pt = 0; pt < 2; ++pt) {
      int pix = pxw + (pt << 4) + cl;
      int e = (pix * 256 + ks * 64 + g * 16) ^ swz;
      af[pt] = *(const bf16x8*)((const char*)xs + e);
    }
    #pragma unroll
    for (int nt = 0; nt < 4; ++nt) {
      bf16x8 bfr = *(const bf16x8*)&c2F[(size_t)((nt << 4) + cl) * 128 + ks * 32 + g * 8];
      acc3[0][nt] = __builtin_amdgcn_mfma_f32_16x16x32_bf16(af[0], bfr, acc3[0][nt], 0, 0, 0);
      acc3[1][nt] = __builtin_amdgcn_mfma_f32_16x16x32_bf16(af[1], bfr, acc3[1][nt], 0, 0, 0);
    }
  }

  // epilogue -> Snp[patch][k'], k' = p*512 + c*4 + q (bf16), p = y&3 fixed
  const int pgrp = (b << 5) + (y >> 2);
  u16* Srow = Snp + ((size_t)pgrp << 16) + ((y & 3) << 9);
  #pragma unroll
  for (int pt = 0; pt < 2; ++pt) {
    int pixr = pxw + (pt << 4) + (g << 2);
    float4 rn4 = *(const float4*)&rn[pixr];
    int pw = pixr >> 2;
    #pragma unroll
    for (int nt = 0; nt < 4; ++nt) {
      int c = (nt << 4) + cl;
      float b1 = conv1_b[c];
      f32x4 a2 = acc2[pt][nt];
      uint2 s0 = { pk2(a2[0] + b1, a2[1] + b1), pk2(a2[2] + b1, a2[3] + b1) };
      *(uint2*)&Srow[((size_t)pw << 11) + (c << 2)] = s0;
      float b2 = conv2_b[c];
      f32x4 a3 = acc3[pt][nt];
      uint2 s1v = { pk2(a3[0] * rn4.x + b2, a3[1] * rn4.y + b2),
                    pk2(a3[2] * rn4.z + b2, a3[3] * rn4.w + b2) };
      *(uint2*)&Srow[((size_t)pw << 11) + ((c + 64) << 2)] = s1v;
    }
  }
}

// ------- kernel BC: fused PatchEmbed GEMM + LN -> (LDS) -> PatchExpand ------
// 512 threads / 8 waves: phase-1 each wave owns ONE 16-chan n-tile; phase-3
// jt = w*4+jj; phase-4 pixl = (w*2+mt4)*16+cl. LDS identical to 4-wave build.
__global__ __launch_bounds__(512) void k_pe_ex(
    const u16* __restrict__ Snp, const u16* __restrict__ pewB,
    const float* __restrict__ pe_b, const float* __restrict__ pe_g,
    const float* __restrict__ pe_beta,
    const u16* __restrict__ expB,
    const float* __restrict__ fin_g, const float* __restrict__ fin_b,
    const u16* __restrict__ upF, const float* __restrict__ up_b,
    u16* __restrict__ M1b)
{
  __shared__ u16 As[8192];        // 16 patches x 512 k, XOR-swizzled (16KB)
  __shared__ float fln[16][132];  // 8.25KB
  __shared__ u16 fb[2048];        // [16 patches][128] bf16, XOR (p&7)<<4 (4KB)
  __shared__ u16 feL[8192];       // (16KB)
  __shared__ u16 feL2[8192];      // (16KB)
  __shared__ float lng[32], lnb[32];
  const int t = threadIdx.x, bx = blockIdx.x;
  const int w = t >> 6, l = t & 63;
  const int g = l >> 4, cl = l & 15;
  const size_t gbase = (size_t)bx << 15;
  const int pg0 = bx << 4;

  if (t < 32) { lng[t] = fin_g[t]; lnb[t] = fin_b[t]; }

  // ---------------- phase 1: PatchEmbed GEMM (M=16, N=128, K=2048) ---------
  // wave w computes n-tile w (16 output chans) for all 16 patches.
  f32x4 acc = (f32x4){0.f, 0.f, 0.f, 0.f};

  for (int chunk = 0; chunk < 4; ++chunk) {
    __syncthreads();
    #pragma unroll
    for (int it = 0; it < 2; ++it) {
      int e8 = ((it << 9) + t) << 3;       // 1024 x 16B total
      int pl = e8 >> 9, kk = e8 & 511;
      uint4 v = *(const uint4*)&Snp[gbase + ((size_t)pl << 11) + (chunk << 9) + kk];
      int e = (((pl << 9) + kk) << 1) ^ ((pl & 7) << 4);
      *(uint4*)((char*)As + e) = v;
    }
    __syncthreads();
    for (int ks = 0; ks < 16; ++ks) {
      int kk = (ks << 5) + (g << 3);
      int e = (((cl << 9) + kk) << 1) ^ ((cl & 7) << 4);
      bf16x8 A = *(const bf16x8*)((const char*)As + e);
      int gks = (chunk << 4) + ks;
      bf16x8 B = *(const bf16x8*)&pewB[(size_t)((((gks << 3) + w) << 6) + l) << 3];
      acc = __builtin_amdgcn_mfma_f32_16x16x32_bf16(A, B, acc, 0, 0, 0);
    }
  }

  {
    int o = (w << 4) + cl;
    float pb = pe_b[o];
    #pragma unroll
    for (int r = 0; r < 4; ++r)
      fln[(g << 2) + r][o] = acc[r] + pb;
  }
  __syncthreads();

  // ------------- phase 2: LN over 128 chans -> fb (LDS, bf16) -------------
  if (t < 128) {
    int patch = t >> 3, sub = t & 7;
    float4 v0 = *(const float4*)&fln[patch][(sub << 4) + 0];
    float4 v1 = *(const float4*)&fln[patch][(sub << 4) + 4];
    float4 v2 = *(const float4*)&fln[patch][(sub << 4) + 8];
    float4 v3 = *(const float4*)&fln[patch][(sub << 4) + 12];
    float s1 = v0.x + v0.y + v0.z + v0.w + v1.x + v1.y + v1.z + v1.w
             + v2.x + v2.y + v2.z + v2.w + v3.x + v3.y + v3.z + v3.w;
    float s2 = v0.x*v0.x + v0.y*v0.y + v0.z*v0.z + v0.w*v0.w
             + v1.x*v1.x + v1.y*v1.y + v1.z*v1.z + v1.w*v1.w
             + v2.x*v2.x + v2.y*v2.y + v2.z*v2.z + v2.w*v2.w
             + v3.x*v3.x + v3.y*v3.y + v3.z*v3.z + v3.w*v3.w;
    s1 += __shfl_xor(s1, 1); s2 += __shfl_xor(s2, 1);
    s1 += __shfl_xor(s1, 2); s2 += __shfl_xor(s2, 2);
    s1 += __shfl_xor(s1, 4); s2 += __shfl_xor(s2, 4);
    float m = s1 * (1.f / 128.f);
    float var = s2 * (1.f / 128.f) - m * m;
    float rs = rsqrtf(var + 1e-5f);
    int o0 = sub << 4;
    #pragma unroll
    for (int i = 0; i < 4; ++i) {
      float4 vv = (i == 0) ? v0 : (i == 1) ? v1 : (i == 2) ? v2 : v3;
      float4 gv = *(const float4*)&pe_g[o0 + (i << 2)];
      float4 bv = *(const float4*)&pe_beta[o0 + (i << 2)];
      uint2 st = { pk2((vv.x - m) * rs * gv.x + bv.x, (vv.y - m) * rs * gv.y + bv.y),
                   pk2((vv.z - m) * rs * gv.z + bv.z, (vv.w - m) * rs * gv.w + bv.w) };
      int c = o0 + (i << 2);
      int e = (patch * 256 + c * 2) ^ ((patch & 7) << 4);
      *(uint2*)((char*)fb + e) = st;
    }
  }
  __syncthreads();

  // ------------- phase 3: PatchExpand GEMM (swapped) + LN(32) -------------
  // wave w: jt = w*4 + jj, jj < 4  (32 jt tiles over 8 waves)
  f32x4 acc1[4];
  #pragma unroll
  for (int jj = 0; jj < 4; ++jj) acc1[jj] = (f32x4){0.f, 0.f, 0.f, 0.f};
  #pragma unroll
  for (int ks = 0; ks < 4; ++ks) {
    int e = (cl * 256 + ks * 64 + g * 16) ^ ((cl & 7) << 4);
    bf16x8 ff = *(const bf16x8*)((const char*)fb + e);
    #pragma unroll
    for (int jj = 0; jj < 4; ++jj) {
      int jt = (w << 2) + jj;
      bf16x8 wf = *(const bf16x8*)&expB[(size_t)((jt << 4) + cl) * 128 + ks * 32 + g * 8];
      acc1[jj] = __builtin_amdgcn_mfma_f32_16x16x32_bf16(wf, ff, acc1[jj], 0, 0, 0);
    }
  }
  // store: lane -> patch = cl, j0 = jt*16 + g*4 (4 consecutive j as bf16)
  #pragma unroll
  for (int jj = 0; jj < 4; ++jj) {
    int j0 = (((w << 2) + jj) << 4) + (g << 2);
    f32x4 a = acc1[jj];
    uint2 st = { pk2(a[0], a[1]), pk2(a[2], a[3]) };
    int e = (cl * 1024 + j0 * 2) ^ ((cl & 7) << 3);
    *(uint2*)((char*)feL + e) = st;
  }
  __syncthreads();

  if (t < 256) { // LN over 32-chan groups; thread t -> pixel t
    int patch = t >> 4, sub = t & 15;
    int rot = t & 15;
    int baseR = patch * 1024 + sub * 64;
    int xr = (patch & 7) << 3;
    float vals[32];
    float s1 = 0.f, s2 = 0.f;
    #pragma unroll
    for (int wd = 0; wd < 16; ++wd) {
      int ww = (wd + rot) & 15;
      u32 u = *(const u32*)((const char*)feL + ((baseR + ww * 4) ^ xr));
      float lo, hi; up2(u, lo, hi);
      vals[wd * 2] = lo; vals[wd * 2 + 1] = hi;
      s1 += lo + hi; s2 += lo * lo + hi * hi;
    }
    float m = s1 * (1.f / 32.f);
    float var = s2 * (1.f / 32.f) - m * m;
    float rs = rsqrtf(var + 1e-5f);
    int baseW = t * 64;
    int xw = (t & 3) << 4;           // 16B-granularity XOR
    #pragma unroll
    for (int wd = 0; wd < 16; ++wd) {
      int ww = (wd + rot) & 15;
      float lo = (vals[wd * 2]     - m) * rs * lng[ww * 2]     + lnb[ww * 2];
      float hi = (vals[wd * 2 + 1] - m) * rs * lng[ww * 2 + 1] + lnb[ww * 2 + 1];
      *(u32*)((char*)feL2 + ((baseW + ww * 4) ^ xw)) = pk2(lo, hi);
    }
  }
  __syncthreads();

  // up-proj (swapped): wave w handles pixl half-tiles (w*2+mt4), mt4 < 2.
  #pragma unroll
  for (int mt4 = 0; mt4 < 2; ++mt4) {
    int pixl = (((w << 1) + mt4) << 4) + cl;
    int e = (pixl * 64 + g * 16) ^ ((pixl & 3) << 4);
    bf16x8 fef = *(const bf16x8*)((const char*)feL2 + e);
    int pglob = pg0 + (pixl >> 4);
    int sub = pixl & 15;
    int bb = pglob >> 10, ph = (pglob >> 5) & 31, pw = pglob & 31;
    int yy = (ph << 2) + (sub >> 2), xx = (pw << 2) + (sub & 3);
    size_t mbase = ((size_t)(((bb << 7) + yy) << 7) + xx) << 7;
    f32x4 accu[8];
    #pragma unroll
    for (int nt = 0; nt < 8; ++nt) {
      bf16x8 wfu = *(const bf16x8*)&upF[((nt << 4) + cl) * 32 + g * 8];
      accu[nt] = __builtin_amdgcn_mfma_f32_16x16x32_bf16(
          wfu, fef, (f32x4){0.f, 0.f, 0.f, 0.f}, 0, 0, 0);
    }
    #pragma unroll
    for (int nt = 0; nt < 8; ++nt) {
      int o0 = (nt << 4) + (g << 2);
      float4 ub4 = *(const float4*)&up_b[o0];
      f32x4 a = accu[nt];
      uint2 st = { pk2(a[0] + ub4.x, a[1] + ub4.y),
                   pk2(a[2] + ub4.z, a[3] + ub4.w) };
      *(uint2*)&M1b[mbase + o0] = st;
    }
  }
}

// ---------------- kernel D: Xn = fwt0*(query@Wpre^T) + fwt1*M1b, MFMA -------
__global__ __launch_bounds__(256) void k_wf(
    const float* __restrict__ Q, const u16* __restrict__ wpreF,
    const u16* __restrict__ M1b, const float* __restrict__ w2,
    u16* __restrict__ Xn)
{
  __shared__ u16 qs[16384];   // [pix=128][c=128] bf16, XOR-swizzled
  const int t = threadIdx.x;
  const int b = blockIdx.x >> 7;
  const int hw0 = (blockIdx.x & 127) << 7;

  { // stage query row (bf16, swizzled)
    const int pix = t & 127, ch = t >> 7;
    const float* Qp = Q + ((size_t)b << 21) + (size_t)hw0 + pix;
    #pragma unroll
    for (int c0 = 0; c0 < 64; c0 += 8) {
      float v[8]; u32 pkv[4];
      #pragma unroll
      for (int j = 0; j < 8; ++j)
        v[j] = Qp[(size_t)(ch * 64 + c0 + j) << 14];
      #pragma unroll
      for (int j = 0; j < 4; ++j) pkv[j] = pk2(v[2 * j], v[2 * j + 1]);
      int e = pix * 256 + (ch * 64 + c0) * 2;
      e ^= (pix & 7) << 4;
      *(uint4*)((char*)qs + e) = *(const uint4*)pkv;
    }
  }
  __syncthreads();

  const int w = t >> 6, l = t & 63;
  const int g = l >> 4, cl = l & 15;
  const int pxw = w << 5;
  const int swz = (cl & 7) << 4;

  f32x4 acc[2][8];
  #pragma unroll
  for (int pt = 0; pt < 2; ++pt)
    #pragma unroll
    for (int ot = 0; ot < 8; ++ot) acc[pt][ot] = (f32x4){0.f, 0.f, 0.f, 0.f};

  #pragma unroll
  for (int ks = 0; ks < 4; ++ks) {
    bf16x8 qf[2];
    #pragma unroll
    for (int pt = 0; pt < 2; ++pt) {
      int pix = pxw + (pt << 4) + cl;
      int e = (pix * 256 + ks * 64 + g * 16) ^ swz;
      qf[pt] = *(const bf16x8*)((const char*)qs + e);
    }
    #pragma unroll
    for (int ot = 0; ot < 8; ++ot) {
      bf16x8 wf = *(const bf16x8*)&wpreF[(size_t)((ot << 4) + cl) * 128 + ks * 32 + g * 8];
      acc[0][ot] = __builtin_amdgcn_mfma_f32_16x16x32_bf16(wf, qf[0], acc[0][ot], 0, 0, 0);
      acc[1][ot] = __builtin_amdgcn_mfma_f32_16x16x32_bf16(wf, qf[1], acc[1][ot], 0, 0, 0);
    }
  }

  float a0 = fmaxf(w2[0], 0.f), a1 = fmaxf(w2[1], 0.f);
  float inv = 1.f / (a0 + a1 + 1e-8f);
  float f0 = a0 * inv, f1 = a1 * inv;

  #pragma unroll
  for (int pt = 0; pt < 2; ++pt) {
    int pix = pxw + (pt << 4) + cl;
    size_t pbase = ((size_t)((b << 14) + hw0 + pix)) << 7;
    #pragma unroll
    for (int ot = 0; ot < 8; ++ot) {
      int o0 = (ot << 4) + (g << 2);
      uint2 mv = *(const uint2*)&M1b[pbase + o0];
      float m0, m1, m2, m3;
      up2(mv.x, m0, m1); up2(mv.y, m2, m3);
      f32x4 a = acc[pt][ot];
      uint2 st = { pk2(f0 * a[0] + f1 * m0, f0 * a[1] + f1 * m1),
                   pk2(f0 * a[2] + f1 * m2, f0 * a[3] + f1 * m3) };
      *(uint2*)&Xn[pbase + o0] = st;
    }
  }
}

// ---------------- kernel E: 3x3 conv (MFMA implicit GEMM) + BN + ReLU6 ------
// 6-tap phases: 48KB wb, 6 phases x 2 barriers = 12 barriers.
__global__ __launch_bounds__(256) void k_conv3(
    const u16* __restrict__ Xn, const u16* __restrict__ wpk,
    const float* __restrict__ bnb, float* __restrict__ out)
{
  __shared__ u16 it[12800];    // 100 rows x 128 ic, XOR-swizzled (25.6KB)
  __shared__ u16 wb[24576];    // 6 taps x 8 n x 64 lanes x 8 e (48KB)
  const int t = threadIdx.x, bx = blockIdx.x;
  const int b = bx >> 8, rem = bx & 255;
  const int ty8 = (rem >> 4) << 3, tx8 = (rem & 15) << 3;
  const int y0 = ty8 - 1, x0 = tx8 - 1;

  for (int idx = t; idx < 1600; idx += 256) {
    int ri = idx >> 4, cc = idx & 15;
    int gy = y0 + ri / 10, gx = x0 + ri % 10;
    uint4 v = {0u, 0u, 0u, 0u};
    if (gy >= 0 && gy < 128 && gx >= 0 && gx < 128)
      v = *(const uint4*)&Xn[(((size_t)(b << 14) + (gy << 7) + gx) << 7) + (cc << 3)];
    int e = (ri << 7) + (cc << 3);
    e ^= (ri & 7) << 3;
    *(uint4*)&it[e] = v;
  }

  const int w = t >> 6, l = t & 63;
  const int g = l >> 4, cl = l & 15;

  f32x4 acc[4][2];
  #pragma unroll
  for (int m = 0; m < 4; ++m)
    #pragma unroll
    for (int nn = 0; nn < 2; ++nn)
      acc[m][nn] = (f32x4){0.f, 0.f, 0.f, 0.f};

  int ri0[4];
  #pragma unroll
  for (int m = 0; m < 4; ++m) {
    int p = (m << 4) + cl;
    ri0[m] = (p >> 3) * 10 + (p & 7);
  }

  #pragma unroll
  for (int p = 0; p < 6; ++p) {
    __syncthreads();   // prior phase's wb reads (and initial it stage) done
    { // stage 6 taps of B fragments: contiguous 48KB from wpk (12/thread)
      const u16* wsrc = wpk + p * 24576;
      #pragma unroll
      for (int j = 0; j < 12; ++j) {
        uint4 v = *(const uint4*)(wsrc + (((j << 8) + t) << 3));
        *(uint4*)((char*)wb + (((j << 8) + t) << 4)) = v;
      }
    }
    __syncthreads();   // wb ready (also covers it on first pass)

    #pragma unroll
    for (int tl = 0; tl < 6; ++tl) {
      const int q = p * 6 + tl;            // global (ks,tap) index 0..35
      const int ks = q / 9, tap = q % 9;
      const int dy = tap / 3, dx = tap % 3;
      bf16x8 A[4];
      #pragma unroll
      for (int m = 0; m < 4; ++m) {
        int ri = ri0[m] + dy * 10 + dx;
        int e = (ri << 7) + (ks << 5) + (g << 3);
        e ^= (ri & 7) << 3;
        A[m] = *(const bf16x8*)&it[e];
      }
      #pragma unroll
      for (int nn = 0; nn < 2; ++nn) {
        int n = (w << 1) + nn;
        bf16x8 B = *(const bf16x8*)((const char*)wb + (((tl << 3) + n) << 10) + (l << 4));
        #pragma unroll
        for (int m = 0; m < 4; ++m)
          acc[m][nn] = __builtin_amdgcn_mfma_f32_16x16x32_bf16(A[m], B, acc[m][nn], 0, 0, 0);
      }
    }
  }

  #pragma unroll
  for (int m = 0; m < 4; ++m) {
    int p = (m << 4) + (g << 2);
    int py = p >> 3, px = p & 7;
    #pragma unroll
    for (int nn = 0; nn < 2; ++nn) {
      int n = (w << 1) + nn;
      int o = (n << 4) + cl;
      float bb = bnb[o];
      f32x4 a = acc[m][nn];
      float4 v = { fminf(fmaxf(a[0] + bb, 0.f), 6.f),
                   fminf(fmaxf(a[1] + bb, 0.f), 6.f),
                   fminf(fmaxf(a[2] + bb, 0.f), 6.f),
                   fminf(fmaxf(a[3] + bb, 0.f), 6.f) };
      *(float4*)&out[((size_t)((b << 7) + o) << 14) + ((ty8 + py) << 7) + tx8 + px] = v;
    }
  }
}

extern "C" void kernel_launch(void* const* d_in, const int* in_sizes, int n_in,
                              void* d_out, int out_size, void* d_ws, size_t ws_size,
                              hipStream_t stream) {
  const float* Structure = (const float*)d_in[0];
  const float* query     = (const float*)d_in[1];
  const float* m_items   = (const float*)d_in[2];
  const float* mod_w     = (const float*)d_in[3];
  const float* mod_b     = (const float*)d_in[4];
  const float* conv1_w   = (const float*)d_in[5];
  const float* conv1_b   = (const float*)d_in[6];
  const float* conv2_w   = (const float*)d_in[7];
  const float* conv2_b   = (const float*)d_in[8];
  const float* pe_w      = (const float*)d_in[9];
  const float* pe_b      = (const float*)d_in[10];
  const float* pe_g      = (const float*)d_in[11];
  const float* pe_beta   = (const float*)d_in[12];
  const float* exp_w     = (const float*)d_in[13];
  const float* fin_g     = (const float*)d_in[14];
  const float* fin_b     = (const float*)d_in[15];
  const float* up_w      = (const float*)d_in[16];
  const float* up_b      = (const float*)d_in[17];
  const float* wf_w2     = (const float*)d_in[18];
  const float* wf_pre_w  = (const float*)d_in[19];
  const float* wf_post_w = (const float*)d_in[20];
  const float* wf_bn_g   = (const float*)d_in[21];
  const float* wf_bn_b   = (const float*)d_in[22];

  char* ws = (char*)d_ws;
  u16*   Snp = (u16*)(ws + 0);               // 16,777,216 B (bf16 im2col, k')
  u16*   expB = (u16*)(ws + 34603008);       //    131,072 B
  u16*   upF  = (u16*)(ws + 34734080);       //      8,192 B
  u16*   M1b = (u16*)(ws + 35651584);        // 16,777,216 B (bf16 NHWC)
  u16*   Xn  = (u16*)(ws + 0);               // alias Snp (dead after k_pe_ex)
  u16* wcomb = (u16*)(ws + 69206016);        // 245,760 B
  u16* c2F   = (u16*)(ws + 69451776);        //  16,384 B
  u16* wpreF = (u16*)(ws + 69468160);        //  32,768 B
  u16* wpk   = (u16*)(ws + 69500928);        // 294,912 B
  u16* pewB  = (u16*)(ws + 69795840);        // 524,288 B -> end 70,320,128 B

  k_prep<<<2448, 256, 0, stream>>>(mod_w, conv1_w, m_items, conv2_w, wf_pre_w,
                                   wf_post_w, wf_bn_g, pe_w, exp_w, up_w,
                                   wcomb, c2F, wpreF, wpk, pewB, expB, upF);
  k_read<<<512, 256, 0, stream>>>(Structure, wcomb, c2F, mod_b,
                                  conv1_b, conv2_b, Snp);
  k_pe_ex<<<256, 512, 0, stream>>>(Snp, pewB, pe_b, pe_g, pe_beta,
                                   expB, fin_g, fin_b, upF, up_b, M1b);
  k_wf<<<512, 256, 0, stream>>>(query, wpreF, M1b, wf_w2, Xn);
  k_conv3<<<1024, 256, 0, stream>>>(Xn, wpk, wf_bn_b, (float*)d_out);
}